// Round 1
// baseline (408.949 us; speedup 1.0000x reference)
//
#include <hip/hip_runtime.h>

#define NR 128        // dst nodes per bucket
#define PART_CH 4096  // edges per partition/count block
typedef unsigned short ushortT;
typedef __attribute__((ext_vector_type(8))) short short8;
typedef __attribute__((ext_vector_type(4))) float float4v;
typedef __attribute__((ext_vector_type(2))) float float2v;

__device__ __forceinline__ unsigned short f32_to_bf16_rne(float f) {
    unsigned u = __float_as_uint(f);
    unsigned r = (u + 0x7fffu + ((u >> 16) & 1u)) >> 16;
    return (unsigned short)r;
}

__device__ __forceinline__ unsigned char f32_to_fp8(float f) {
    return (unsigned char)(__builtin_amdgcn_cvt_pk_fp8_f32(f, f, 0, false) & 0xff);
}

__device__ __forceinline__ void accum8(float* acc, uint4 v) {
    unsigned u[4] = {v.x, v.y, v.z, v.w};
#pragma unroll
    for (int q = 0; q < 4; q++) {
        acc[2 * q]     += __uint_as_float(u[q] << 16);
        acc[2 * q + 1] += __uint_as_float(u[q] & 0xffff0000u);
    }
}

// ---------------- CSR build: bucketed counting sort (R7-measured form + batched loads) --

__launch_bounds__(256)
__global__ void bucket_count(const int* __restrict__ dst, int* __restrict__ bcnt, int E, int NB) {
    __shared__ int h[1024];
    int t = threadIdx.x;
    for (int j = t; j < NB; j += 256) h[j] = 0;
    __syncthreads();
    int e0 = blockIdx.x * PART_CH;
    int e1 = min(e0 + PART_CH, E);
    for (int base = e0; base < e1; base += 2048) {
        int idx = base + t;
        int d[8];
        int cnt = 0;
#pragma unroll
        for (int u = 0; u < 8; u++) {
            int e = idx + u * 256;
            if (e < e1) d[cnt++] = dst[e];
        }
        for (int u = 0; u < cnt; u++) atomicAdd(&h[d[u] >> 7], 1);
    }
    __syncthreads();
    for (int j = t; j < NB; j += 256) {
        int v = h[j];
        if (v) atomicAdd(&bcnt[j], v);
    }
}

__launch_bounds__(256)
__global__ void bucket_scan(const int* __restrict__ bcnt, int* __restrict__ bstart,
                            int* __restrict__ gcur, int NB, int E) {
    __shared__ int sh[256];
    int t = threadIdx.x;
    int v[4];
    int tot = 0;
#pragma unroll
    for (int j = 0; j < 4; j++) {
        int idx = t * 4 + j;
        v[j] = (idx < NB) ? bcnt[idx] : 0;
        tot += v[j];
    }
    sh[t] = tot;
    __syncthreads();
    for (int off = 1; off < 256; off <<= 1) {
        int add = (t >= off) ? sh[t - off] : 0;
        __syncthreads();
        sh[t] += add;
        __syncthreads();
    }
    int run = sh[t] - tot;
#pragma unroll
    for (int j = 0; j < 4; j++) {
        int idx = t * 4 + j;
        if (idx < NB) { bstart[idx] = run; gcur[idx] = run; }
        run += v[j];
    }
    if (t == 0) bstart[NB] = E;
}

// partition edges into buckets; packed record = src | (dst&127)<<17  (src < 2^17)
__launch_bounds__(256)
__global__ void partition_edges(const int* __restrict__ src, const int* __restrict__ dst,
                                int* __restrict__ gcur, unsigned* __restrict__ packed,
                                int E, int NB) {
    __shared__ int hist[1024];
    __shared__ int base[1024];
    int t = threadIdx.x;
    int e0 = blockIdx.x * PART_CH;
    int e1 = min(e0 + PART_CH, E);
    for (int j = t; j < NB; j += 256) hist[j] = 0;
    __syncthreads();
    for (int bb = e0; bb < e1; bb += 2048) {
        int idx = bb + t;
        int d[8];
        int cnt = 0;
#pragma unroll
        for (int u = 0; u < 8; u++) {
            int e = idx + u * 256;
            if (e < e1) d[cnt++] = dst[e];
        }
        for (int u = 0; u < cnt; u++) atomicAdd(&hist[d[u] >> 7], 1);
    }
    __syncthreads();
    for (int j = t; j < NB; j += 256) {
        int h = hist[j];
        base[j] = h ? atomicAdd(&gcur[j], h) : 0;
    }
    __syncthreads();
    for (int j = t; j < NB; j += 256) hist[j] = base[j];
    __syncthreads();
    for (int bb = e0; bb < e1; bb += 2048) {
        int idx = bb + t;
        int d[8], s[8];
        int cnt = 0;
#pragma unroll
        for (int u = 0; u < 8; u++) {
            int e = idx + u * 256;
            if (e < e1) { d[cnt] = dst[e]; s[cnt] = src[e]; cnt++; }
        }
        for (int u = 0; u < cnt; u++) {
            int dd = d[u];
            int pos = atomicAdd(&hist[dd >> 7], 1);
            packed[pos] = (unsigned)s[u] | ((unsigned)(dd & (NR - 1)) << 17);
        }
    }
}

__launch_bounds__(256)
__global__ void bucket_sort(const unsigned* __restrict__ packed, const int* __restrict__ bstart,
                            int* __restrict__ row_start, int* __restrict__ srcs, int N) {
    __shared__ int cnt[NR];
    __shared__ int sc[NR];
    __shared__ int cur[NR];
    int b = blockIdx.x, t = threadIdx.x;
    int nb0 = b * NR;
    int nnode = min(NR, N - nb0);
    int lo = bstart[b], hi = bstart[b + 1];
    if (t < NR) cnt[t] = 0;
    __syncthreads();
    for (int bb = lo; bb < hi; bb += 2048) {
        int idx = bb + t;
        unsigned pk[8];
        int c = 0;
#pragma unroll
        for (int u = 0; u < 8; u++) {
            int e = idx + u * 256;
            if (e < hi) pk[c++] = packed[e];
        }
        for (int u = 0; u < c; u++) atomicAdd(&cnt[pk[u] >> 17], 1);
    }
    __syncthreads();
    if (t < NR) sc[t] = cnt[t];
    __syncthreads();
    for (int off = 1; off < NR; off <<= 1) {
        int add = (t >= off && t < NR) ? sc[t - off] : 0;
        __syncthreads();
        if (t < NR) sc[t] += add;
        __syncthreads();
    }
    if (t < nnode) {
        int s = lo + sc[t] - cnt[t];
        row_start[nb0 + t] = s;
        cur[t] = s;
    }
    if (t == 0 && nb0 + nnode == N) row_start[N] = hi;
    __syncthreads();
    for (int bb = lo; bb < hi; bb += 2048) {
        int idx = bb + t;
        unsigned pk[8];
        int c = 0;
#pragma unroll
        for (int u = 0; u < 8; u++) {
            int e = idx + u * 256;
            if (e < hi) pk[c++] = packed[e];
        }
        for (int u = 0; u < c; u++) {
            int pos = atomicAdd(&cur[pk[u] >> 17], 1);
            srcs[pos] = (int)(pk[u] & 0x1FFFFu);
        }
    }
}

// ---------------- fused prep: x -> bf16 + all weight transposes ----------------
// Wt layout: Wt[col][(k + 8*col) % KT] = bf16(Wcat[k][col])

__global__ void prep_fused(const float* __restrict__ x, ushortT* __restrict__ xbf, int n4,
                           const float* __restrict__ Wl0, const float* __restrict__ Wr0,
                           const float* __restrict__ Wl1, const float* __restrict__ Wr1,
                           const float* __restrict__ Wl2, const float* __restrict__ Wr2,
                           const float* __restrict__ Wa2,
                           ushortT* __restrict__ Wt0, ushortT* __restrict__ Wt1,
                           ushortT* __restrict__ Wt2, ushortT* __restrict__ Wa2t) {
    int tid0 = blockIdx.x * 256 + threadIdx.x;
    if (tid0 < n4) {
        float4 v = ((const float4*)x)[tid0];
        ushort4 o;
        o.x = f32_to_bf16_rne(v.x);
        o.y = f32_to_bf16_rne(v.y);
        o.z = f32_to_bf16_rne(v.z);
        o.w = f32_to_bf16_rne(v.w);
        ((ushort4*)xbf)[tid0] = o;
        return;
    }
    int tid = tid0 - n4;
    if (tid < 8192) {  // Wt0: KH=32, KT=64
        int col = tid >> 6, k = tid & 63;
        float v = (k < 32) ? Wl0[k * 128 + col] : Wr0[(k - 32) * 128 + col];
        Wt0[col * 64 + ((k + 8 * col) & 63)] = f32_to_bf16_rne(v);
    } else if (tid < 8192 + 32768) {  // Wt1: KT=256
        int j = tid - 8192;
        int col = j >> 8, k = j & 255;
        float v = (k < 128) ? Wl1[k * 128 + col] : Wr1[(k - 128) * 128 + col];
        Wt1[col * 256 + ((k + 8 * col) & 255)] = f32_to_bf16_rne(v);
    } else if (tid < 8192 + 65536) {  // Wt2: KT=256
        int j = tid - 8192 - 32768;
        int col = j >> 8, k = j & 255;
        float v = (k < 128) ? Wl2[k * 128 + col] : Wr2[(k - 128) * 128 + col];
        Wt2[col * 256 + ((k + 8 * col) & 255)] = f32_to_bf16_rne(v);
    } else if (tid < 8192 + 65536 + 16384) {  // Wa2t: KT=128
        int j = tid - 8192 - 65536;
        int col = j >> 7, k = j & 127;
        Wa2t[col * 128 + ((k + 8 * col) & 127)] = f32_to_bf16_rne(Wa2[k * 128 + col]);
    }
}

// ---------------- fused aggregation + MFMA GEMM ----------------
// Aggregation accumulates the mean DIRECTLY into the MFMA A-fragment each lane needs:
// lane (q,cid) of wave wv owns rows r0c=blk*128+wv*32+cid, r1c=r0c+16, feats ks*32+q*8..+8.
// 4 q-lanes per row together read each neighbor's full row (coalesced / L1-shared lines).
// Numerically identical to the old agg-kernel path (f32 accumulate -> *inv -> RNE bf16).

template <bool FP8, int NKS>
__device__ __forceinline__ void gather_accum(const void* __restrict__ gat, int s, int q, float* ag) {
    if constexpr (FP8) {
        const uint2* hp = (const uint2*)gat;   // row = 128 fp8 = 16 uint2
        size_t base = (size_t)s * 16 + q;
        uint2 c[NKS];
#pragma unroll
        for (int ks = 0; ks < NKS; ks++) c[ks] = hp[base + ks * 4];
#pragma unroll
        for (int ks = 0; ks < NKS; ks++) {
            float2v l0 = __builtin_amdgcn_cvt_pk_f32_fp8(c[ks].x, false);
            float2v h0 = __builtin_amdgcn_cvt_pk_f32_fp8(c[ks].x, true);
            float2v l1 = __builtin_amdgcn_cvt_pk_f32_fp8(c[ks].y, false);
            float2v h1 = __builtin_amdgcn_cvt_pk_f32_fp8(c[ks].y, true);
            ag[ks * 8 + 0] += l0.x; ag[ks * 8 + 1] += l0.y;
            ag[ks * 8 + 2] += h0.x; ag[ks * 8 + 3] += h0.y;
            ag[ks * 8 + 4] += l1.x; ag[ks * 8 + 5] += l1.y;
            ag[ks * 8 + 6] += h1.x; ag[ks * 8 + 7] += h1.y;
        }
    } else {
        const uint4* xp = (const uint4*)gat;   // row = 32 bf16 = 4 uint4
        uint4 v = xp[(size_t)s * 4 + q];
        accum8(ag, v);
    }
}

template <int KH, bool IN_FP8>
__launch_bounds__(256, 2)
__global__ void gemm_agg(const void* __restrict__ gat, const ushortT* __restrict__ Ah,
                         const int* __restrict__ srcs, const int* __restrict__ rs,
                         const ushortT* __restrict__ Wt, const float* __restrict__ bias,
                         ushortT* __restrict__ outbf, unsigned char* __restrict__ outf8, int n) {
    constexpr int KT = 2 * KH;
    constexpr int NKS = KH / 32;
    __shared__ __attribute__((aligned(16))) ushortT sW[128 * KT];
    int t = threadIdx.x;
    constexpr int TOT16 = 128 * KT * 2 / 16;
    {
        const uint4* Wg = (const uint4*)Wt;
        uint4* Ws = (uint4*)sW;
#pragma unroll
        for (int j = 0; j < TOT16 / 256; j++) Ws[t + j * 256] = Wg[t + j * 256];
    }
    int wv = t >> 6, lane = t & 63;
    int q = lane >> 4, cid = lane & 15;
    int rbase = blockIdx.x * 128 + wv * 32;
    int r0 = rbase + cid, r1 = r0 + 16;
    int r0c = min(r0, n - 1), r1c = min(r1, n - 1);

    // ---- register aggregation (mean of neighbor rows, this lane's feature slice)
    float ag0[NKS * 8], ag1[NKS * 8];
#pragma unroll
    for (int j = 0; j < NKS * 8; j++) { ag0[j] = 0.f; ag1[j] = 0.f; }
    int lo0 = rs[r0c], n0 = rs[r0c + 1] - lo0;
    int lo1 = rs[r1c], n1 = rs[r1c + 1] - lo1;
    int mx = max(n0, n1);
    for (int i = 0; i < mx; i += 2) {
        bool v00 = i < n0, v01 = (i + 1) < n0;
        bool v10 = i < n1, v11 = (i + 1) < n1;
        int s00 = srcs[v00 ? lo0 + i : 0];
        int s01 = srcs[v01 ? lo0 + i + 1 : 0];
        int s10 = srcs[v10 ? lo1 + i : 0];
        int s11 = srcs[v11 ? lo1 + i + 1 : 0];
        if (v00) gather_accum<IN_FP8, NKS>(gat, s00, q, ag0);
        if (v01) gather_accum<IN_FP8, NKS>(gat, s01, q, ag0);
        if (v10) gather_accum<IN_FP8, NKS>(gat, s10, q, ag1);
        if (v11) gather_accum<IN_FP8, NKS>(gat, s11, q, ag1);
    }
    float inv0 = 1.0f / (float)max(n0, 1);
    float inv1 = 1.0f / (float)max(n1, 1);
    short8 am0[NKS], am1[NKS];
#pragma unroll
    for (int ks = 0; ks < NKS; ks++)
#pragma unroll
        for (int j = 0; j < 8; j++) {
            am0[ks][j] = (short)f32_to_bf16_rne(ag0[ks * 8 + j] * inv0);
            am1[ks][j] = (short)f32_to_bf16_rne(ag1[ks * 8 + j] * inv1);
        }
    __syncthreads();   // sW ready

    // ---- MFMA main loop
    float4v acc[2][8];
#pragma unroll
    for (int i = 0; i < 2; i++)
#pragma unroll
        for (int j = 0; j < 8; j++) acc[i][j] = (float4v){0.f, 0.f, 0.f, 0.f};
    int swz = q * 8 + 8 * cid;
#pragma unroll
    for (int ks = 0; ks < KT / 32; ++ks) {
        int kk = ks * 32;
        short8 a0, a1;
        if (ks < NKS) {
            a0 = am0[ks];
            a1 = am1[ks];
        } else {
            int kc = kk - KH;
            a0 = *(const short8*)(Ah + (size_t)r0c * KH + kc + q * 8);
            a1 = *(const short8*)(Ah + (size_t)r1c * KH + kc + q * 8);
        }
#pragma unroll
        for (int j = 0; j < 8; ++j) {
            int col = j * 16 + cid;
            int p = (kk + swz + j * 128) & (KT - 1);
            short8 b = *(const short8*)(sW + col * KT + p);
            acc[0][j] = __builtin_amdgcn_mfma_f32_16x16x32_bf16(a0, b, acc[0][j], 0, 0, 0);
            acc[1][j] = __builtin_amdgcn_mfma_f32_16x16x32_bf16(a1, b, acc[1][j], 0, 0, 0);
        }
    }
    float bo[8];
#pragma unroll
    for (int j = 0; j < 8; ++j) bo[j] = bias[j * 16 + cid];
#pragma unroll
    for (int i = 0; i < 2; ++i) {
#pragma unroll
        for (int rr = 0; rr < 4; ++rr) {
            int row = rbase + i * 16 + q * 4 + rr;
            if (row < n) {
#pragma unroll
                for (int j = 0; j < 8; ++j) {
                    int col = j * 16 + cid;
                    float v = fmaxf(acc[i][j][rr] + bo[j], 0.f);
                    outbf[(size_t)row * 128 + col] = f32_to_bf16_rne(v);
                    outf8[(size_t)row * 128 + col] = f32_to_fp8(v);
                }
            }
        }
    }
}

// ---- layer-2 variant: fused aggregation + GEMM + d1/d3 epilogue + aux-head MLP.
// d1/d3 stay block-local in LDS; Wa2t reuses the sW buffer after the main loop.

__launch_bounds__(256, 2)
__global__ void gemm_agg_fin(const void* __restrict__ gat, const ushortT* __restrict__ Ah,
                             const int* __restrict__ srcs, const int* __restrict__ rs,
                             const ushortT* __restrict__ Wt, const float* __restrict__ bias,
                             const float* __restrict__ Wfc, const float* __restrict__ bfc,
                             const ushortT* __restrict__ Wa2t, const float* __restrict__ Wa1,
                             const float* __restrict__ ba1, const float* __restrict__ ba2,
                             const float* __restrict__ Wao, const float* __restrict__ bao,
                             float* __restrict__ fin, int n) {
    constexpr int KH = 128, KT = 256, NKS = 4;
    __shared__ __attribute__((aligned(16))) ushortT sW[128 * KT];   // 64 KB
    __shared__ float sD1[128], sD3[128];
    __shared__ float sWa1a[128], sWa1b[128], sBa1[128];
    int t = threadIdx.x;
    {
        const uint4* Wg = (const uint4*)Wt;
        uint4* Ws = (uint4*)sW;
#pragma unroll
        for (int j = 0; j < 16; j++) Ws[t + j * 256] = Wg[t + j * 256];
    }
    if (t < 128) { sWa1a[t] = Wa1[t]; sWa1b[t] = Wa1[128 + t]; sBa1[t] = ba1[t]; }
    int wv = t >> 6, lane = t & 63;
    int q = lane >> 4, cid = lane & 15;
    int blk0 = blockIdx.x * 128;
    int rbase = blk0 + wv * 32;
    int r0 = rbase + cid, r1 = r0 + 16;
    int r0c = min(r0, n - 1), r1c = min(r1, n - 1);

    // ---- register aggregation
    float ag0[NKS * 8], ag1[NKS * 8];
#pragma unroll
    for (int j = 0; j < NKS * 8; j++) { ag0[j] = 0.f; ag1[j] = 0.f; }
    int lo0 = rs[r0c], n0 = rs[r0c + 1] - lo0;
    int lo1 = rs[r1c], n1 = rs[r1c + 1] - lo1;
    int mx = max(n0, n1);
    for (int i = 0; i < mx; i += 2) {
        bool v00 = i < n0, v01 = (i + 1) < n0;
        bool v10 = i < n1, v11 = (i + 1) < n1;
        int s00 = srcs[v00 ? lo0 + i : 0];
        int s01 = srcs[v01 ? lo0 + i + 1 : 0];
        int s10 = srcs[v10 ? lo1 + i : 0];
        int s11 = srcs[v11 ? lo1 + i + 1 : 0];
        if (v00) gather_accum<true, NKS>(gat, s00, q, ag0);
        if (v01) gather_accum<true, NKS>(gat, s01, q, ag0);
        if (v10) gather_accum<true, NKS>(gat, s10, q, ag1);
        if (v11) gather_accum<true, NKS>(gat, s11, q, ag1);
    }
    float inv0 = 1.0f / (float)max(n0, 1);
    float inv1 = 1.0f / (float)max(n1, 1);
    short8 am0[NKS], am1[NKS];
#pragma unroll
    for (int ks = 0; ks < NKS; ks++)
#pragma unroll
        for (int j = 0; j < 8; j++) {
            am0[ks][j] = (short)f32_to_bf16_rne(ag0[ks * 8 + j] * inv0);
            am1[ks][j] = (short)f32_to_bf16_rne(ag1[ks * 8 + j] * inv1);
        }
    __syncthreads();   // sW ready

    // ---- MFMA main loop
    float4v acc[2][8];
#pragma unroll
    for (int i = 0; i < 2; i++)
#pragma unroll
        for (int j = 0; j < 8; j++) acc[i][j] = (float4v){0.f, 0.f, 0.f, 0.f};
    int swz = q * 8 + 8 * cid;
#pragma unroll
    for (int ks = 0; ks < KT / 32; ++ks) {
        int kk = ks * 32;
        short8 a0, a1;
        if (ks < NKS) {
            a0 = am0[ks];
            a1 = am1[ks];
        } else {
            int kc = kk - KH;
            a0 = *(const short8*)(Ah + (size_t)r0c * KH + kc + q * 8);
            a1 = *(const short8*)(Ah + (size_t)r1c * KH + kc + q * 8);
        }
#pragma unroll
        for (int j = 0; j < 8; ++j) {
            int col = j * 16 + cid;
            int p = (kk + swz + j * 128) & (KT - 1);
            short8 b = *(const short8*)(sW + col * KT + p);
            acc[0][j] = __builtin_amdgcn_mfma_f32_16x16x32_bf16(a0, b, acc[0][j], 0, 0, 0);
            acc[1][j] = __builtin_amdgcn_mfma_f32_16x16x32_bf16(a1, b, acc[1][j], 0, 0, 0);
        }
    }

    // ---- epilogue: d1/d3 -> fin[:,0], fin[:,2] + block-local LDS
    float bo[8], w1[8], w3[8];
#pragma unroll
    for (int j = 0; j < 8; ++j) {
        int col = j * 16 + cid;
        bo[j] = bias[col];
        w1[j] = Wfc[col * 3 + 0];
        w3[j] = Wfc[col * 3 + 2];
    }
    float bfc0 = bfc[0], bfc2 = bfc[2];
#pragma unroll
    for (int i = 0; i < 2; ++i) {
#pragma unroll
        for (int rr = 0; rr < 4; ++rr) {
            float p1 = 0.f, p3 = 0.f;
#pragma unroll
            for (int j = 0; j < 8; ++j) {
                float v = fmaxf(acc[i][j][rr] + bo[j], 0.f);
                p1 += v * w1[j];
                p3 += v * w3[j];
            }
            p1 += __shfl_xor(p1, 1, 64); p3 += __shfl_xor(p3, 1, 64);
            p1 += __shfl_xor(p1, 2, 64); p3 += __shfl_xor(p3, 2, 64);
            p1 += __shfl_xor(p1, 4, 64); p3 += __shfl_xor(p3, 4, 64);
            p1 += __shfl_xor(p1, 8, 64); p3 += __shfl_xor(p3, 8, 64);
            int rowl = wv * 32 + i * 16 + q * 4 + rr;
            if (cid == 0) {
                float d1 = p1 + bfc0, d3 = p3 + bfc2;
                sD1[rowl] = d1;
                sD3[rowl] = d3;
                int row = blk0 + rowl;
                if (row < n) {
                    fin[(size_t)row * 3 + 0] = d1;
                    fin[(size_t)row * 3 + 2] = d3;
                }
            }
        }
    }
    __syncthreads();   // sD ready; everyone done reading sW

    // ---- reload sW (first 32 KB) with Wa2t
    {
        const uint4* Wg = (const uint4*)Wa2t;
        uint4* Ws = (uint4*)sW;
#pragma unroll
        for (int j = 0; j < 8; j++) Ws[t + j * 256] = Wg[t + j * 256];
    }
    __syncthreads();

    // ---- aux head: a1 built in registers + a2 MFMA + Wao reduce -> fin[:,1]
    int rl0 = wv * 32 + cid, rl1 = rl0 + 16;
    float d1a = sD1[rl0], d3a = sD3[rl0];
    float d1b = sD1[rl1], d3b = sD3[rl1];
    float4v hacc[2][8];
#pragma unroll
    for (int i = 0; i < 2; i++)
#pragma unroll
        for (int j = 0; j < 8; j++) hacc[i][j] = (float4v){0.f, 0.f, 0.f, 0.f};
#pragma unroll
    for (int ks = 0; ks < 4; ++ks) {
        int k0 = ks * 32 + q * 8;
        short8 a0, a1;
#pragma unroll
        for (int j = 0; j < 8; ++j) {
            int k = k0 + j;
            float w0 = sWa1a[k], w1h = sWa1b[k], bb = sBa1[k];
            float v0 = fmaxf(fmaf(d1a, w0, fmaf(d3a, w1h, bb)), 0.f);
            float v1 = fmaxf(fmaf(d1b, w0, fmaf(d3b, w1h, bb)), 0.f);
            a0[j] = (short)f32_to_bf16_rne(v0);
            a1[j] = (short)f32_to_bf16_rne(v1);
        }
        int p = (ks * 32 + swz) & 127;
#pragma unroll
        for (int j = 0; j < 8; ++j) {
            short8 b = *(const short8*)(sW + (j * 16 + cid) * 128 + p);
            hacc[0][j] = __builtin_amdgcn_mfma_f32_16x16x32_bf16(a0, b, hacc[0][j], 0, 0, 0);
            hacc[1][j] = __builtin_amdgcn_mfma_f32_16x16x32_bf16(a1, b, hacc[1][j], 0, 0, 0);
        }
    }
    float b2[8], wo[8];
#pragma unroll
    for (int j = 0; j < 8; ++j) {
        int col = j * 16 + cid;
        b2[j] = ba2[col];
        wo[j] = Wao[col];
    }
    float bao0 = bao[0];
#pragma unroll
    for (int i = 0; i < 2; ++i) {
#pragma unroll
        for (int rr = 0; rr < 4; ++rr) {
            float s = 0.f;
#pragma unroll
            for (int j = 0; j < 8; ++j) s += fmaxf(hacc[i][j][rr] + b2[j], 0.f) * wo[j];
            s += __shfl_xor(s, 1, 64);
            s += __shfl_xor(s, 2, 64);
            s += __shfl_xor(s, 4, 64);
            s += __shfl_xor(s, 8, 64);
            int row = blk0 + wv * 32 + i * 16 + q * 4 + rr;
            if (cid == 0 && row < n) fin[(size_t)row * 3 + 1] = s + bao0;
        }
    }
}

// ---------------- per-graph mean pool ----------------

__global__ void pool_kernel(const float* __restrict__ fin, const int* __restrict__ batch,
                            float* __restrict__ out, int n) {
    int g = blockIdx.x, t = threadIdx.x;
    int lo = 0, hi = n;
    while (lo < hi) { int mid = (lo + hi) >> 1; if (batch[mid] < g) lo = mid + 1; else hi = mid; }
    int start = lo;
    lo = 0; hi = n;
    while (lo < hi) { int mid = (lo + hi) >> 1; if (batch[mid] < g + 1) lo = mid + 1; else hi = mid; }
    int end = lo;
    float s0 = 0.f, s1 = 0.f, s2 = 0.f;
    for (int i = start + t; i < end; i += 256) {
        s0 += fin[(size_t)i * 3 + 0];
        s1 += fin[(size_t)i * 3 + 1];
        s2 += fin[(size_t)i * 3 + 2];
    }
    __shared__ float r0[256], r1[256], r2[256];
    r0[t] = s0; r1[t] = s1; r2[t] = s2;
    __syncthreads();
    for (int off = 128; off > 0; off >>= 1) {
        if (t < off) { r0[t] += r0[t + off]; r1[t] += r1[t + off]; r2[t] += r2[t + off]; }
        __syncthreads();
    }
    if (t == 0) {
        float c = (float)max(end - start, 1);
        out[g * 3 + 0] = r0[0] / c;
        out[g * 3 + 1] = r1[0] / c;
        out[g * 3 + 2] = r2[0] / c;
    }
}

// ---------------- launch ----------------

extern "C" void kernel_launch(void* const* d_in, const int* in_sizes, int n_in,
                              void* d_out, int out_size, void* d_ws, size_t ws_size,
                              hipStream_t stream) {
    const float* x    = (const float*)d_in[0];
    const int*   ei   = (const int*)d_in[1];
    const int*   batch= (const int*)d_in[2];
    const float* Wl0  = (const float*)d_in[3];
    const float* bl0  = (const float*)d_in[4];
    const float* Wr0  = (const float*)d_in[5];
    const float* Wl1  = (const float*)d_in[6];
    const float* bl1  = (const float*)d_in[7];
    const float* Wr1  = (const float*)d_in[8];
    const float* Wl2  = (const float*)d_in[9];
    const float* bl2  = (const float*)d_in[10];
    const float* Wr2  = (const float*)d_in[11];
    const float* Wfc  = (const float*)d_in[12];
    const float* bfc  = (const float*)d_in[13];
    const float* Wa1  = (const float*)d_in[14];
    const float* ba1  = (const float*)d_in[15];
    const float* Wa2  = (const float*)d_in[16];
    const float* ba2  = (const float*)d_in[17];
    const float* Wao  = (const float*)d_in[18];
    const float* bao  = (const float*)d_in[19];

    const int N = in_sizes[0] / 32;
    const int E = in_sizes[1] / 2;
    const int G = out_size / 3;
    const int* src = ei;
    const int* dst = ei + E;
    float* out = (float*)d_out;
    const int NB = (N + NR - 1) / NR;

    char* p = (char*)d_ws;
    auto carve = [&](size_t bytes) {
        void* r = (void*)p;
        p += (bytes + 255) & ~(size_t)255;
        return r;
    };
    int*           bcnt     = (int*)carve((size_t)NB * 4);
    int*           bstart   = (int*)carve((size_t)(NB + 1) * 4);
    int*           gcur     = (int*)carve((size_t)NB * 4);
    int*           row_start= (int*)carve((size_t)(N + 1) * 4);
    unsigned*      packed   = (unsigned*)carve((size_t)E * 4);
    int*           srcs     = (int*)carve((size_t)E * 4);
    ushortT*       xbf      = (ushortT*)carve((size_t)N * 32 * 2);
    ushortT*       hbf0     = (ushortT*)carve((size_t)N * 128 * 2);
    ushortT*       hbf1     = (ushortT*)carve((size_t)N * 128 * 2);
    unsigned char* hf8_0    = (unsigned char*)carve((size_t)N * 128);
    unsigned char* hf8_1    = (unsigned char*)carve((size_t)N * 128);
    float*         fin      = (float*)carve((size_t)N * 3 * 4);
    ushortT*       Wt0      = (ushortT*)carve((size_t)128 * 64 * 2);
    ushortT*       Wt1      = (ushortT*)carve((size_t)128 * 256 * 2);
    ushortT*       Wt2      = (ushortT*)carve((size_t)128 * 256 * 2);
    ushortT*       Wa2t     = (ushortT*)carve((size_t)128 * 128 * 2);

    const int gemm_grid = (N + 127) / 128;
    const int part_grid = (E + PART_CH - 1) / PART_CH;
    const int n4 = N * 32 / 4;

    // fused input/weight prep
    prep_fused<<<(n4 + 90112 + 255) / 256, 256, 0, stream>>>(
        x, xbf, n4, Wl0, Wr0, Wl1, Wr1, Wl2, Wr2, Wa2, Wt0, Wt1, Wt2, Wa2t);

    // CSR build (R7-measured bucketed counting sort, batched loads)
    hipMemsetAsync(bcnt, 0, (size_t)NB * 4, stream);
    bucket_count<<<part_grid, 256, 0, stream>>>(dst, bcnt, E, NB);
    bucket_scan<<<1, 256, 0, stream>>>(bcnt, bstart, gcur, NB, E);
    partition_edges<<<part_grid, 256, 0, stream>>>(src, dst, gcur, packed, E, NB);
    bucket_sort<<<NB, 256, 0, stream>>>(packed, bstart, row_start, srcs, N);

    // layer 0 (KH=32): fused bf16 gather + GEMM; dual-write h0 (bf16 + fp8)
    gemm_agg<32, false><<<gemm_grid, 256, 0, stream>>>(
        (const void*)xbf, xbf, srcs, row_start, Wt0, bl0, hbf0, hf8_0, N);
    // layer 1 (KH=128): fused fp8 gather + GEMM; dual-write h1
    gemm_agg<128, true><<<gemm_grid, 256, 0, stream>>>(
        (const void*)hf8_0, hbf0, srcs, row_start, Wt1, bl1, hbf1, hf8_1, N);
    // layer 2 (KH=128): fused fp8 gather + GEMM + d1/d3 epilogue + aux head -> fin
    gemm_agg_fin<<<gemm_grid, 256, 0, stream>>>(
        (const void*)hf8_1, hbf1, srcs, row_start, Wt2, bl2, Wfc, bfc,
        Wa2t, Wa1, ba1, ba2, Wao, bao, fin, N);

    // per-graph mean pool
    pool_kernel<<<G, 256, 0, stream>>>(fin, batch, out, N);
}

// Round 2
// 368.542 us; speedup vs baseline: 1.1096x; 1.1096x over previous
//
#include <hip/hip_runtime.h>

#define NR 128        // dst nodes per bucket
#define PART_CH 4096  // edges per partition/count block
typedef unsigned short ushortT;
typedef __attribute__((ext_vector_type(8))) short short8;
typedef __attribute__((ext_vector_type(4))) float float4v;
typedef __attribute__((ext_vector_type(2))) float float2v;

__device__ __forceinline__ unsigned short f32_to_bf16_rne(float f) {
    unsigned u = __float_as_uint(f);
    unsigned r = (u + 0x7fffu + ((u >> 16) & 1u)) >> 16;
    return (unsigned short)r;
}

__device__ __forceinline__ unsigned char f32_to_fp8(float f) {
    return (unsigned char)(__builtin_amdgcn_cvt_pk_fp8_f32(f, f, 0, false) & 0xff);
}

__device__ __forceinline__ void accum8(float* acc, uint4 v) {
    unsigned u[4] = {v.x, v.y, v.z, v.w};
#pragma unroll
    for (int q = 0; q < 4; q++) {
        acc[2 * q]     += __uint_as_float(u[q] << 16);
        acc[2 * q + 1] += __uint_as_float(u[q] & 0xffff0000u);
    }
}

// 32 fp8 bytes (two uint4, lane's contiguous permuted slice) -> ag[32]
__device__ __forceinline__ void accum32_fp8(float* ag, uint4 A, uint4 B) {
    unsigned w[8] = {A.x, A.y, A.z, A.w, B.x, B.y, B.z, B.w};
#pragma unroll
    for (int m = 0; m < 8; m++) {
        float2v lo = __builtin_amdgcn_cvt_pk_f32_fp8(w[m], false);
        float2v hi = __builtin_amdgcn_cvt_pk_f32_fp8(w[m], true);
        ag[4 * m + 0] += lo.x;
        ag[4 * m + 1] += lo.y;
        ag[4 * m + 2] += hi.x;
        ag[4 * m + 3] += hi.y;
    }
}

// ---------------- CSR build: bucketed counting sort ----------------

__launch_bounds__(256)
__global__ void bucket_count(const int* __restrict__ dst, int* __restrict__ bcnt, int E, int NB) {
    __shared__ int h[1024];
    int t = threadIdx.x;
    for (int j = t; j < NB; j += 256) h[j] = 0;
    __syncthreads();
    int e0 = blockIdx.x * PART_CH;
    int e1 = min(e0 + PART_CH, E);
    for (int base = e0; base < e1; base += 2048) {
        int idx = base + t;
        int d[8];
        int cnt = 0;
#pragma unroll
        for (int u = 0; u < 8; u++) {
            int e = idx + u * 256;
            if (e < e1) d[cnt++] = dst[e];
        }
        for (int u = 0; u < cnt; u++) atomicAdd(&h[d[u] >> 7], 1);
    }
    __syncthreads();
    for (int j = t; j < NB; j += 256) {
        int v = h[j];
        if (v) atomicAdd(&bcnt[j], v);
    }
}

__launch_bounds__(256)
__global__ void bucket_scan(const int* __restrict__ bcnt, int* __restrict__ bstart,
                            int* __restrict__ gcur, int NB, int E) {
    __shared__ int sh[256];
    int t = threadIdx.x;
    int v[4];
    int tot = 0;
#pragma unroll
    for (int j = 0; j < 4; j++) {
        int idx = t * 4 + j;
        v[j] = (idx < NB) ? bcnt[idx] : 0;
        tot += v[j];
    }
    sh[t] = tot;
    __syncthreads();
    for (int off = 1; off < 256; off <<= 1) {
        int add = (t >= off) ? sh[t - off] : 0;
        __syncthreads();
        sh[t] += add;
        __syncthreads();
    }
    int run = sh[t] - tot;
#pragma unroll
    for (int j = 0; j < 4; j++) {
        int idx = t * 4 + j;
        if (idx < NB) { bstart[idx] = run; gcur[idx] = run; }
        run += v[j];
    }
    if (t == 0) bstart[NB] = E;
}

__launch_bounds__(256)
__global__ void partition_edges(const int* __restrict__ src, const int* __restrict__ dst,
                                int* __restrict__ gcur, unsigned* __restrict__ packed,
                                int E, int NB) {
    __shared__ int hist[1024];
    __shared__ int base[1024];
    int t = threadIdx.x;
    int e0 = blockIdx.x * PART_CH;
    int e1 = min(e0 + PART_CH, E);
    for (int j = t; j < NB; j += 256) hist[j] = 0;
    __syncthreads();
    for (int bb = e0; bb < e1; bb += 2048) {
        int idx = bb + t;
        int d[8];
        int cnt = 0;
#pragma unroll
        for (int u = 0; u < 8; u++) {
            int e = idx + u * 256;
            if (e < e1) d[cnt++] = dst[e];
        }
        for (int u = 0; u < cnt; u++) atomicAdd(&hist[d[u] >> 7], 1);
    }
    __syncthreads();
    for (int j = t; j < NB; j += 256) {
        int h = hist[j];
        base[j] = h ? atomicAdd(&gcur[j], h) : 0;
    }
    __syncthreads();
    for (int j = t; j < NB; j += 256) hist[j] = base[j];
    __syncthreads();
    for (int bb = e0; bb < e1; bb += 2048) {
        int idx = bb + t;
        int d[8], s[8];
        int cnt = 0;
#pragma unroll
        for (int u = 0; u < 8; u++) {
            int e = idx + u * 256;
            if (e < e1) { d[cnt] = dst[e]; s[cnt] = src[e]; cnt++; }
        }
        for (int u = 0; u < cnt; u++) {
            int dd = d[u];
            int pos = atomicAdd(&hist[dd >> 7], 1);
            packed[pos] = (unsigned)s[u] | ((unsigned)(dd & (NR - 1)) << 17);
        }
    }
}

__launch_bounds__(256)
__global__ void bucket_sort(const unsigned* __restrict__ packed, const int* __restrict__ bstart,
                            int* __restrict__ row_start, int* __restrict__ srcs, int N) {
    __shared__ int cnt[NR];
    __shared__ int sc[NR];
    __shared__ int cur[NR];
    int b = blockIdx.x, t = threadIdx.x;
    int nb0 = b * NR;
    int nnode = min(NR, N - nb0);
    int lo = bstart[b], hi = bstart[b + 1];
    if (t < NR) cnt[t] = 0;
    __syncthreads();
    for (int bb = lo; bb < hi; bb += 2048) {
        int idx = bb + t;
        unsigned pk[8];
        int c = 0;
#pragma unroll
        for (int u = 0; u < 8; u++) {
            int e = idx + u * 256;
            if (e < hi) pk[c++] = packed[e];
        }
        for (int u = 0; u < c; u++) atomicAdd(&cnt[pk[u] >> 17], 1);
    }
    __syncthreads();
    if (t < NR) sc[t] = cnt[t];
    __syncthreads();
    for (int off = 1; off < NR; off <<= 1) {
        int add = (t >= off && t < NR) ? sc[t - off] : 0;
        __syncthreads();
        if (t < NR) sc[t] += add;
        __syncthreads();
    }
    if (t < nnode) {
        int s = lo + sc[t] - cnt[t];
        row_start[nb0 + t] = s;
        cur[t] = s;
    }
    if (t == 0 && nb0 + nnode == N) row_start[N] = hi;
    __syncthreads();
    for (int bb = lo; bb < hi; bb += 2048) {
        int idx = bb + t;
        unsigned pk[8];
        int c = 0;
#pragma unroll
        for (int u = 0; u < 8; u++) {
            int e = idx + u * 256;
            if (e < hi) pk[c++] = packed[e];
        }
        for (int u = 0; u < c; u++) {
            int pos = atomicAdd(&cur[pk[u] >> 17], 1);
            srcs[pos] = (int)(pk[u] & 0x1FFFFu);
        }
    }
}

// ---------------- fused prep: x -> bf16 + all weight transposes ----------------
// Wt0 layout (KT=64, single stage): Wt0[col*64 + ((k + 8*col) & 63)]
// Wt1/Wt2 layout (KT=256, two 32KB halves of 128 k each):
//   h = k>>7; Wt[h*16384 + col*128 + (((k&127) + 8*col) & 127)]
// Wa2t layout (KT=128): Wa2t[col*128 + ((k + 8*col) & 127)]

__global__ void prep_fused(const float* __restrict__ x, ushortT* __restrict__ xbf, int n4,
                           const float* __restrict__ Wl0, const float* __restrict__ Wr0,
                           const float* __restrict__ Wl1, const float* __restrict__ Wr1,
                           const float* __restrict__ Wl2, const float* __restrict__ Wr2,
                           const float* __restrict__ Wa2,
                           ushortT* __restrict__ Wt0, ushortT* __restrict__ Wt1,
                           ushortT* __restrict__ Wt2, ushortT* __restrict__ Wa2t) {
    int tid0 = blockIdx.x * 256 + threadIdx.x;
    if (tid0 < n4) {
        float4 v = ((const float4*)x)[tid0];
        ushort4 o;
        o.x = f32_to_bf16_rne(v.x);
        o.y = f32_to_bf16_rne(v.y);
        o.z = f32_to_bf16_rne(v.z);
        o.w = f32_to_bf16_rne(v.w);
        ((ushort4*)xbf)[tid0] = o;
        return;
    }
    int tid = tid0 - n4;
    if (tid < 8192) {  // Wt0: KH=32, KT=64
        int col = tid >> 6, k = tid & 63;
        float v = (k < 32) ? Wl0[k * 128 + col] : Wr0[(k - 32) * 128 + col];
        Wt0[col * 64 + ((k + 8 * col) & 63)] = f32_to_bf16_rne(v);
    } else if (tid < 8192 + 32768) {  // Wt1
        int j = tid - 8192;
        int col = j >> 8, k = j & 255;
        float v = (k < 128) ? Wl1[k * 128 + col] : Wr1[(k - 128) * 128 + col];
        Wt1[(k >> 7) * 16384 + col * 128 + (((k & 127) + 8 * col) & 127)] = f32_to_bf16_rne(v);
    } else if (tid < 8192 + 65536) {  // Wt2
        int j = tid - 8192 - 32768;
        int col = j >> 8, k = j & 255;
        float v = (k < 128) ? Wl2[k * 128 + col] : Wr2[(k - 128) * 128 + col];
        Wt2[(k >> 7) * 16384 + col * 128 + (((k & 127) + 8 * col) & 127)] = f32_to_bf16_rne(v);
    } else if (tid < 8192 + 65536 + 16384) {  // Wa2t
        int j = tid - 8192 - 65536;
        int col = j >> 7, k = j & 127;
        Wa2t[col * 128 + ((k + 8 * col) & 127)] = f32_to_bf16_rne(Wa2[k * 128 + col]);
    }
}

// ---------------- gather helpers (batch-8, src-prefetch, branch-free loads) ------------
// fp8 h layout is PERMUTED: feature f stored at byte ((f>>3)&3)*32 + (f>>5)*8 + (f&7),
// so lane q's A-slice (features ks*32+q*8..+8, ks=0..3) is 32 contiguous bytes at q*32.

__device__ __forceinline__ void gather_fp8(const uint4* __restrict__ hp, const int* __restrict__ srcs,
                                           int lo, int deg, int q, float* ag) {
    int nb = (deg + 7) >> 3;
    if (nb == 0) return;
    int last = lo + deg - 1;
    int sA[8];
#pragma unroll
    for (int u = 0; u < 8; u++) sA[u] = srcs[min(lo + u, last)];
    for (int b = 0; b < nb; b++) {
        uint4 va[8], vb[8];
#pragma unroll
        for (int u = 0; u < 8; u++) {
            size_t bs = (size_t)sA[u] * 8 + q * 2;
            va[u] = hp[bs];
            vb[u] = hp[bs + 1];
        }
        int e0 = lo + (b + 1) * 8;
        if (b + 1 < nb) {
#pragma unroll
            for (int u = 0; u < 8; u++) sA[u] = srcs[min(e0 + u, last)];
        }
        int rem = deg - b * 8;
#pragma unroll
        for (int u = 0; u < 8; u++)
            if (u < rem) accum32_fp8(ag, va[u], vb[u]);
    }
}

__device__ __forceinline__ void gather_bf16(const uint4* __restrict__ xp, const int* __restrict__ srcs,
                                            int lo, int deg, int q, float* ag) {
    int nb = (deg + 7) >> 3;
    if (nb == 0) return;
    int last = lo + deg - 1;
    int sA[8];
#pragma unroll
    for (int u = 0; u < 8; u++) sA[u] = srcs[min(lo + u, last)];
    for (int b = 0; b < nb; b++) {
        uint4 va[8];
#pragma unroll
        for (int u = 0; u < 8; u++) va[u] = xp[(size_t)sA[u] * 4 + q];
        int e0 = lo + (b + 1) * 8;
        if (b + 1 < nb) {
#pragma unroll
            for (int u = 0; u < 8; u++) sA[u] = srcs[min(e0 + u, last)];
        }
        int rem = deg - b * 8;
#pragma unroll
        for (int u = 0; u < 8; u++)
            if (u < rem) accum8(ag, va[u]);
    }
}

// ---------------- fused aggregation + MFMA GEMM (BM=64, split-K staging) ---------------
// Each lane owns ONE row (wv*16+cid) and its full A-fragment set; 4 blocks/CU.

template <int KH, bool IN_FP8>
__launch_bounds__(256, 4)
__global__ void gemm_agg(const void* __restrict__ gat, const ushortT* __restrict__ Ah,
                         const int* __restrict__ srcs, const int* __restrict__ rs,
                         const ushortT* __restrict__ Wt, const float* __restrict__ bias,
                         ushortT* __restrict__ outbf, unsigned char* __restrict__ outf8, int n) {
    constexpr int NKS = KH / 32;
    constexpr int KTH = (KH == 32) ? 64 : 128;   // staged k-extent
    __shared__ __attribute__((aligned(16))) ushortT sW[128 * KTH];
    int t = threadIdx.x;
    {
        const uint4* Wg = (const uint4*)Wt;
        uint4* Ws = (uint4*)sW;
#pragma unroll
        for (int j = 0; j < (128 * KTH / 8) / 256; j++) Ws[t + j * 256] = Wg[t + j * 256];
    }
    int wv = t >> 6, lane = t & 63;
    int q = lane >> 4, cid = lane & 15;
    int row = blockIdx.x * 64 + wv * 16 + cid;
    int rc = min(row, n - 1);

    // ---- register aggregation (mean of neighbor rows, this lane's feature slice)
    float ag[NKS * 8];
#pragma unroll
    for (int j = 0; j < NKS * 8; j++) ag[j] = 0.f;
    int lo = rs[rc], deg = rs[rc + 1] - lo;
    if constexpr (IN_FP8) gather_fp8((const uint4*)gat, srcs, lo, deg, q, ag);
    else                  gather_bf16((const uint4*)gat, srcs, lo, deg, q, ag);
    float inv = 1.0f / (float)max(deg, 1);
    short8 am[NKS];
#pragma unroll
    for (int ks = 0; ks < NKS; ks++)
#pragma unroll
        for (int j = 0; j < 8; j++) am[ks][j] = (short)f32_to_bf16_rne(ag[ks * 8 + j] * inv);
    __syncthreads();   // sW (stage 0) ready

    float4v acc[8];
#pragma unroll
    for (int j = 0; j < 8; j++) acc[j] = (float4v){0.f, 0.f, 0.f, 0.f};
    int pbase = q * 8 + 8 * cid;
    // half 0: A = aggregated mean (registers)
#pragma unroll
    for (int ks = 0; ks < NKS; ks++) {
        int p = (ks * 32 + pbase) & (KTH - 1);
#pragma unroll
        for (int j = 0; j < 8; ++j) {
            short8 b = *(const short8*)(sW + (j * 16 + cid) * KTH + p);
            acc[j] = __builtin_amdgcn_mfma_f32_16x16x32_bf16(am[ks], b, acc[j], 0, 0, 0);
        }
    }
    // half 1: A = Ah (global)
    if constexpr (KH == 32) {
        short8 ah = *(const short8*)(Ah + (size_t)rc * 32 + q * 8);
        int p = (32 + pbase) & 63;
#pragma unroll
        for (int j = 0; j < 8; ++j) {
            short8 b = *(const short8*)(sW + (j * 16 + cid) * 64 + p);
            acc[j] = __builtin_amdgcn_mfma_f32_16x16x32_bf16(ah, b, acc[j], 0, 0, 0);
        }
    } else {
        short8 ah[4];
#pragma unroll
        for (int ks = 0; ks < 4; ks++)
            ah[ks] = *(const short8*)(Ah + (size_t)rc * 128 + ks * 32 + q * 8);
        __syncthreads();   // done reading stage 0
        {
            const uint4* Wg = (const uint4*)(Wt + 128 * 128);
            uint4* Ws = (uint4*)sW;
#pragma unroll
            for (int j = 0; j < 8; j++) Ws[t + j * 256] = Wg[t + j * 256];
        }
        __syncthreads();   // stage 1 ready
#pragma unroll
        for (int ks = 0; ks < 4; ks++) {
            int p = (ks * 32 + pbase) & 127;
#pragma unroll
            for (int j = 0; j < 8; ++j) {
                short8 b = *(const short8*)(sW + (j * 16 + cid) * 128 + p);
                acc[j] = __builtin_amdgcn_mfma_f32_16x16x32_bf16(ah[ks], b, acc[j], 0, 0, 0);
            }
        }
    }
    // epilogue: relu + bias; dual-write bf16 (linear) + fp8 (permuted)
    float bo[8];
#pragma unroll
    for (int j = 0; j < 8; ++j) bo[j] = bias[j * 16 + cid];
    int orow = blockIdx.x * 64 + wv * 16 + q * 4;
#pragma unroll
    for (int rr = 0; rr < 4; ++rr) {
        int r = orow + rr;
        if (r < n) {
#pragma unroll
            for (int j = 0; j < 8; ++j) {
                int col = j * 16 + cid;
                float v = fmaxf(acc[j][rr] + bo[j], 0.f);
                outbf[(size_t)r * 128 + col] = f32_to_bf16_rne(v);
                int pc = ((col >> 3) & 3) * 32 + ((col >> 5) << 3) + (col & 7);
                outf8[(size_t)r * 128 + pc] = f32_to_fp8(v);
            }
        }
    }
}

// ---- layer-2 variant: fused aggregation + GEMM + d1/d3 epilogue + aux-head MLP --------

__launch_bounds__(256, 4)
__global__ void gemm_agg_fin(const void* __restrict__ gat, const ushortT* __restrict__ Ah,
                             const int* __restrict__ srcs, const int* __restrict__ rs,
                             const ushortT* __restrict__ Wt, const float* __restrict__ bias,
                             const float* __restrict__ Wfc, const float* __restrict__ bfc,
                             const ushortT* __restrict__ Wa2t, const float* __restrict__ Wa1,
                             const float* __restrict__ ba1, const float* __restrict__ ba2,
                             const float* __restrict__ Wao, const float* __restrict__ bao,
                             float* __restrict__ fin, int n) {
    __shared__ __attribute__((aligned(16))) ushortT sW[128 * 128];   // 32 KB
    __shared__ float sD1[64], sD3[64];
    __shared__ float sWa1a[128], sWa1b[128], sBa1[128];
    int t = threadIdx.x;
    {
        const uint4* Wg = (const uint4*)Wt;
        uint4* Ws = (uint4*)sW;
#pragma unroll
        for (int j = 0; j < 8; j++) Ws[t + j * 256] = Wg[t + j * 256];
    }
    if (t < 128) { sWa1a[t] = Wa1[t]; sWa1b[t] = Wa1[128 + t]; sBa1[t] = ba1[t]; }
    int wv = t >> 6, lane = t & 63;
    int q = lane >> 4, cid = lane & 15;
    int row = blockIdx.x * 64 + wv * 16 + cid;
    int rc = min(row, n - 1);

    float ag[32];
#pragma unroll
    for (int j = 0; j < 32; j++) ag[j] = 0.f;
    int lo = rs[rc], deg = rs[rc + 1] - lo;
    gather_fp8((const uint4*)gat, srcs, lo, deg, q, ag);
    float inv = 1.0f / (float)max(deg, 1);
    short8 am[4];
#pragma unroll
    for (int ks = 0; ks < 4; ks++)
#pragma unroll
        for (int j = 0; j < 8; j++) am[ks][j] = (short)f32_to_bf16_rne(ag[ks * 8 + j] * inv);
    __syncthreads();   // sW stage 0 ready

    float4v acc[8];
#pragma unroll
    for (int j = 0; j < 8; j++) acc[j] = (float4v){0.f, 0.f, 0.f, 0.f};
    int pbase = q * 8 + 8 * cid;
#pragma unroll
    for (int ks = 0; ks < 4; ks++) {
        int p = (ks * 32 + pbase) & 127;
#pragma unroll
        for (int j = 0; j < 8; ++j) {
            short8 b = *(const short8*)(sW + (j * 16 + cid) * 128 + p);
            acc[j] = __builtin_amdgcn_mfma_f32_16x16x32_bf16(am[ks], b, acc[j], 0, 0, 0);
        }
    }
    short8 ah[4];
#pragma unroll
    for (int ks = 0; ks < 4; ks++)
        ah[ks] = *(const short8*)(Ah + (size_t)rc * 128 + ks * 32 + q * 8);
    __syncthreads();
    {
        const uint4* Wg = (const uint4*)(Wt + 128 * 128);
        uint4* Ws = (uint4*)sW;
#pragma unroll
        for (int j = 0; j < 8; j++) Ws[t + j * 256] = Wg[t + j * 256];
    }
    __syncthreads();
#pragma unroll
    for (int ks = 0; ks < 4; ks++) {
        int p = (ks * 32 + pbase) & 127;
#pragma unroll
        for (int j = 0; j < 8; ++j) {
            short8 b = *(const short8*)(sW + (j * 16 + cid) * 128 + p);
            acc[j] = __builtin_amdgcn_mfma_f32_16x16x32_bf16(ah[ks], b, acc[j], 0, 0, 0);
        }
    }

    // ---- epilogue: d1/d3 -> fin[:,0], fin[:,2] + block-local LDS
    float bo[8], w1[8], w3[8];
#pragma unroll
    for (int j = 0; j < 8; ++j) {
        int col = j * 16 + cid;
        bo[j] = bias[col];
        w1[j] = Wfc[col * 3 + 0];
        w3[j] = Wfc[col * 3 + 2];
    }
    float bfc0 = bfc[0], bfc2 = bfc[2];
#pragma unroll
    for (int rr = 0; rr < 4; ++rr) {
        float p1 = 0.f, p3 = 0.f;
#pragma unroll
        for (int j = 0; j < 8; ++j) {
            float v = fmaxf(acc[j][rr] + bo[j], 0.f);
            p1 += v * w1[j];
            p3 += v * w3[j];
        }
        p1 += __shfl_xor(p1, 1, 64); p3 += __shfl_xor(p3, 1, 64);
        p1 += __shfl_xor(p1, 2, 64); p3 += __shfl_xor(p3, 2, 64);
        p1 += __shfl_xor(p1, 4, 64); p3 += __shfl_xor(p3, 4, 64);
        p1 += __shfl_xor(p1, 8, 64); p3 += __shfl_xor(p3, 8, 64);
        if (cid == 0) {
            int rowl = wv * 16 + q * 4 + rr;
            float d1 = p1 + bfc0, d3 = p3 + bfc2;
            sD1[rowl] = d1;
            sD3[rowl] = d3;
            int r = blockIdx.x * 64 + rowl;
            if (r < n) {
                fin[(size_t)r * 3 + 0] = d1;
                fin[(size_t)r * 3 + 2] = d3;
            }
        }
    }
    __syncthreads();   // sD ready; everyone done reading sW
    {
        const uint4* Wg = (const uint4*)Wa2t;
        uint4* Ws = (uint4*)sW;
#pragma unroll
        for (int j = 0; j < 8; j++) Ws[t + j * 256] = Wg[t + j * 256];
    }
    __syncthreads();

    // ---- aux head: a1 built in registers + a2 MFMA + Wao reduce -> fin[:,1]
    int rl = wv * 16 + cid;
    float d1a = sD1[rl], d3a = sD3[rl];
    float4v hacc[8];
#pragma unroll
    for (int j = 0; j < 8; j++) hacc[j] = (float4v){0.f, 0.f, 0.f, 0.f};
#pragma unroll
    for (int ks = 0; ks < 4; ++ks) {
        int k0 = ks * 32 + q * 8;
        short8 a0;
#pragma unroll
        for (int j = 0; j < 8; ++j) {
            int k = k0 + j;
            float v0 = fmaxf(fmaf(d1a, sWa1a[k], fmaf(d3a, sWa1b[k], sBa1[k])), 0.f);
            a0[j] = (short)f32_to_bf16_rne(v0);
        }
        int p = (ks * 32 + pbase) & 127;
#pragma unroll
        for (int j = 0; j < 8; ++j) {
            short8 b = *(const short8*)(sW + (j * 16 + cid) * 128 + p);
            hacc[j] = __builtin_amdgcn_mfma_f32_16x16x32_bf16(a0, b, hacc[j], 0, 0, 0);
        }
    }
    float b2[8], wo[8];
#pragma unroll
    for (int j = 0; j < 8; ++j) {
        int col = j * 16 + cid;
        b2[j] = ba2[col];
        wo[j] = Wao[col];
    }
    float bao0 = bao[0];
#pragma unroll
    for (int rr = 0; rr < 4; ++rr) {
        float s = 0.f;
#pragma unroll
        for (int j = 0; j < 8; ++j) s += fmaxf(hacc[j][rr] + b2[j], 0.f) * wo[j];
        s += __shfl_xor(s, 1, 64);
        s += __shfl_xor(s, 2, 64);
        s += __shfl_xor(s, 4, 64);
        s += __shfl_xor(s, 8, 64);
        int r = blockIdx.x * 64 + wv * 16 + q * 4 + rr;
        if (cid == 0 && r < n) fin[(size_t)r * 3 + 1] = s + bao0;
    }
}

// ---------------- per-graph mean pool ----------------

__global__ void pool_kernel(const float* __restrict__ fin, const int* __restrict__ batch,
                            float* __restrict__ out, int n) {
    int g = blockIdx.x, t = threadIdx.x;
    int lo = 0, hi = n;
    while (lo < hi) { int mid = (lo + hi) >> 1; if (batch[mid] < g) lo = mid + 1; else hi = mid; }
    int start = lo;
    lo = 0; hi = n;
    while (lo < hi) { int mid = (lo + hi) >> 1; if (batch[mid] < g + 1) lo = mid + 1; else hi = mid; }
    int end = lo;
    float s0 = 0.f, s1 = 0.f, s2 = 0.f;
    for (int i = start + t; i < end; i += 256) {
        s0 += fin[(size_t)i * 3 + 0];
        s1 += fin[(size_t)i * 3 + 1];
        s2 += fin[(size_t)i * 3 + 2];
    }
    __shared__ float r0[256], r1[256], r2[256];
    r0[t] = s0; r1[t] = s1; r2[t] = s2;
    __syncthreads();
    for (int off = 128; off > 0; off >>= 1) {
        if (t < off) { r0[t] += r0[t + off]; r1[t] += r1[t + off]; r2[t] += r2[t + off]; }
        __syncthreads();
    }
    if (t == 0) {
        float c = (float)max(end - start, 1);
        out[g * 3 + 0] = r0[0] / c;
        out[g * 3 + 1] = r1[0] / c;
        out[g * 3 + 2] = r2[0] / c;
    }
}

// ---------------- launch ----------------

extern "C" void kernel_launch(void* const* d_in, const int* in_sizes, int n_in,
                              void* d_out, int out_size, void* d_ws, size_t ws_size,
                              hipStream_t stream) {
    const float* x    = (const float*)d_in[0];
    const int*   ei   = (const int*)d_in[1];
    const int*   batch= (const int*)d_in[2];
    const float* Wl0  = (const float*)d_in[3];
    const float* bl0  = (const float*)d_in[4];
    const float* Wr0  = (const float*)d_in[5];
    const float* Wl1  = (const float*)d_in[6];
    const float* bl1  = (const float*)d_in[7];
    const float* Wr1  = (const float*)d_in[8];
    const float* Wl2  = (const float*)d_in[9];
    const float* bl2  = (const float*)d_in[10];
    const float* Wr2  = (const float*)d_in[11];
    const float* Wfc  = (const float*)d_in[12];
    const float* bfc  = (const float*)d_in[13];
    const float* Wa1  = (const float*)d_in[14];
    const float* ba1  = (const float*)d_in[15];
    const float* Wa2  = (const float*)d_in[16];
    const float* ba2  = (const float*)d_in[17];
    const float* Wao  = (const float*)d_in[18];
    const float* bao  = (const float*)d_in[19];

    const int N = in_sizes[0] / 32;
    const int E = in_sizes[1] / 2;
    const int G = out_size / 3;
    const int* src = ei;
    const int* dst = ei + E;
    float* out = (float*)d_out;
    const int NB = (N + NR - 1) / NR;

    char* p = (char*)d_ws;
    auto carve = [&](size_t bytes) {
        void* r = (void*)p;
        p += (bytes + 255) & ~(size_t)255;
        return r;
    };
    int*           bcnt     = (int*)carve((size_t)NB * 4);
    int*           bstart   = (int*)carve((size_t)(NB + 1) * 4);
    int*           gcur     = (int*)carve((size_t)NB * 4);
    int*           row_start= (int*)carve((size_t)(N + 1) * 4);
    unsigned*      packed   = (unsigned*)carve((size_t)E * 4);
    int*           srcs     = (int*)carve((size_t)E * 4);
    ushortT*       xbf      = (ushortT*)carve((size_t)N * 32 * 2);
    ushortT*       hbf0     = (ushortT*)carve((size_t)N * 128 * 2);
    ushortT*       hbf1     = (ushortT*)carve((size_t)N * 128 * 2);
    unsigned char* hf8_0    = (unsigned char*)carve((size_t)N * 128);
    unsigned char* hf8_1    = (unsigned char*)carve((size_t)N * 128);
    float*         fin      = (float*)carve((size_t)N * 3 * 4);
    ushortT*       Wt0      = (ushortT*)carve((size_t)128 * 64 * 2);
    ushortT*       Wt1      = (ushortT*)carve((size_t)128 * 256 * 2);
    ushortT*       Wt2      = (ushortT*)carve((size_t)128 * 256 * 2);
    ushortT*       Wa2t     = (ushortT*)carve((size_t)128 * 128 * 2);

    const int gemm_grid = (N + 63) / 64;
    const int part_grid = (E + PART_CH - 1) / PART_CH;
    const int n4 = N * 32 / 4;

    // fused input/weight prep
    prep_fused<<<(n4 + 90112 + 255) / 256, 256, 0, stream>>>(
        x, xbf, n4, Wl0, Wr0, Wl1, Wr1, Wl2, Wr2, Wa2, Wt0, Wt1, Wt2, Wa2t);

    // CSR build
    hipMemsetAsync(bcnt, 0, (size_t)NB * 4, stream);
    bucket_count<<<part_grid, 256, 0, stream>>>(dst, bcnt, E, NB);
    bucket_scan<<<1, 256, 0, stream>>>(bcnt, bstart, gcur, NB, E);
    partition_edges<<<part_grid, 256, 0, stream>>>(src, dst, gcur, packed, E, NB);
    bucket_sort<<<NB, 256, 0, stream>>>(packed, bstart, row_start, srcs, N);

    // layer 0 (KH=32): fused bf16 gather + GEMM; dual-write h0 (bf16 + permuted fp8)
    gemm_agg<32, false><<<gemm_grid, 256, 0, stream>>>(
        (const void*)xbf, xbf, srcs, row_start, Wt0, bl0, hbf0, hf8_0, N);
    // layer 1 (KH=128): fused fp8 gather + GEMM; dual-write h1
    gemm_agg<128, true><<<gemm_grid, 256, 0, stream>>>(
        (const void*)hf8_0, hbf0, srcs, row_start, Wt1, bl1, hbf1, hf8_1, N);
    // layer 2 (KH=128): fused fp8 gather + GEMM + d1/d3 epilogue + aux head -> fin
    gemm_agg_fin<<<gemm_grid, 256, 0, stream>>>(
        (const void*)hf8_1, hbf1, srcs, row_start, Wt2, bl2, Wfc, bfc,
        Wa2t, Wa1, ba1, ba2, Wao, bao, fin, N);

    // per-graph mean pool
    pool_kernel<<<G, 256, 0, stream>>>(fin, batch, out, N);
}

// Round 3
// 358.131 us; speedup vs baseline: 1.1419x; 1.0291x over previous
//
#include <hip/hip_runtime.h>

#define NR 128        // dst nodes per bucket
#define PART_CH 4096  // edges per partition/count block
typedef unsigned short ushortT;
typedef __attribute__((ext_vector_type(8))) short short8;
typedef __attribute__((ext_vector_type(4))) float float4v;
typedef __attribute__((ext_vector_type(2))) float float2v;

__device__ __forceinline__ unsigned short f32_to_bf16_rne(float f) {
    unsigned u = __float_as_uint(f);
    unsigned r = (u + 0x7fffu + ((u >> 16) & 1u)) >> 16;
    return (unsigned short)r;
}

__device__ __forceinline__ unsigned char f32_to_fp8(float f) {
    return (unsigned char)(__builtin_amdgcn_cvt_pk_fp8_f32(f, f, 0, false) & 0xff);
}

__device__ __forceinline__ void accum8(float* acc, uint4 v) {
    unsigned u[4] = {v.x, v.y, v.z, v.w};
#pragma unroll
    for (int q = 0; q < 4; q++) {
        acc[2 * q]     += __uint_as_float(u[q] << 16);
        acc[2 * q + 1] += __uint_as_float(u[q] & 0xffff0000u);
    }
}

// 32 fp8 bytes (two uint4, lane's contiguous permuted slice) -> ag[32]
__device__ __forceinline__ void accum32_fp8(float* ag, uint4 A, uint4 B) {
    unsigned w[8] = {A.x, A.y, A.z, A.w, B.x, B.y, B.z, B.w};
#pragma unroll
    for (int m = 0; m < 8; m++) {
        float2v lo = __builtin_amdgcn_cvt_pk_f32_fp8(w[m], false);
        float2v hi = __builtin_amdgcn_cvt_pk_f32_fp8(w[m], true);
        ag[4 * m + 0] += lo.x;
        ag[4 * m + 1] += lo.y;
        ag[4 * m + 2] += hi.x;
        ag[4 * m + 3] += hi.y;
    }
}

// ---------------- CSR build: bucketed counting sort ----------------

__launch_bounds__(256)
__global__ void bucket_count(const int* __restrict__ dst, int* __restrict__ bcnt, int E, int NB) {
    __shared__ int h[1024];
    int t = threadIdx.x;
    for (int j = t; j < NB; j += 256) h[j] = 0;
    __syncthreads();
    int e0 = blockIdx.x * PART_CH;
    int e1 = min(e0 + PART_CH, E);
    for (int base = e0; base < e1; base += 2048) {
        int idx = base + t;
        int d[8];
        int cnt = 0;
#pragma unroll
        for (int u = 0; u < 8; u++) {
            int e = idx + u * 256;
            if (e < e1) d[cnt++] = dst[e];
        }
        for (int u = 0; u < cnt; u++) atomicAdd(&h[d[u] >> 7], 1);
    }
    __syncthreads();
    for (int j = t; j < NB; j += 256) {
        int v = h[j];
        if (v) atomicAdd(&bcnt[j], v);
    }
}

__launch_bounds__(256)
__global__ void bucket_scan(const int* __restrict__ bcnt, int* __restrict__ bstart,
                            int* __restrict__ gcur, int NB, int E) {
    __shared__ int sh[256];
    int t = threadIdx.x;
    int v[4];
    int tot = 0;
#pragma unroll
    for (int j = 0; j < 4; j++) {
        int idx = t * 4 + j;
        v[j] = (idx < NB) ? bcnt[idx] : 0;
        tot += v[j];
    }
    sh[t] = tot;
    __syncthreads();
    for (int off = 1; off < 256; off <<= 1) {
        int add = (t >= off) ? sh[t - off] : 0;
        __syncthreads();
        sh[t] += add;
        __syncthreads();
    }
    int run = sh[t] - tot;
#pragma unroll
    for (int j = 0; j < 4; j++) {
        int idx = t * 4 + j;
        if (idx < NB) { bstart[idx] = run; gcur[idx] = run; }
        run += v[j];
    }
    if (t == 0) bstart[NB] = E;
}

__launch_bounds__(256)
__global__ void partition_edges(const int* __restrict__ src, const int* __restrict__ dst,
                                int* __restrict__ gcur, unsigned* __restrict__ packed,
                                int E, int NB) {
    __shared__ int hist[1024];
    __shared__ int base[1024];
    int t = threadIdx.x;
    int e0 = blockIdx.x * PART_CH;
    int e1 = min(e0 + PART_CH, E);
    for (int j = t; j < NB; j += 256) hist[j] = 0;
    __syncthreads();
    for (int bb = e0; bb < e1; bb += 2048) {
        int idx = bb + t;
        int d[8];
        int cnt = 0;
#pragma unroll
        for (int u = 0; u < 8; u++) {
            int e = idx + u * 256;
            if (e < e1) d[cnt++] = dst[e];
        }
        for (int u = 0; u < cnt; u++) atomicAdd(&hist[d[u] >> 7], 1);
    }
    __syncthreads();
    for (int j = t; j < NB; j += 256) {
        int h = hist[j];
        base[j] = h ? atomicAdd(&gcur[j], h) : 0;
    }
    __syncthreads();
    for (int j = t; j < NB; j += 256) hist[j] = base[j];
    __syncthreads();
    for (int bb = e0; bb < e1; bb += 2048) {
        int idx = bb + t;
        int d[8], s[8];
        int cnt = 0;
#pragma unroll
        for (int u = 0; u < 8; u++) {
            int e = idx + u * 256;
            if (e < e1) { d[cnt] = dst[e]; s[cnt] = src[e]; cnt++; }
        }
        for (int u = 0; u < cnt; u++) {
            int dd = d[u];
            int pos = atomicAdd(&hist[dd >> 7], 1);
            packed[pos] = (unsigned)s[u] | ((unsigned)(dd & (NR - 1)) << 17);
        }
    }
}

__launch_bounds__(256)
__global__ void bucket_sort(const unsigned* __restrict__ packed, const int* __restrict__ bstart,
                            int* __restrict__ row_start, int* __restrict__ srcs, int N) {
    __shared__ int cnt[NR];
    __shared__ int sc[NR];
    __shared__ int cur[NR];
    int b = blockIdx.x, t = threadIdx.x;
    int nb0 = b * NR;
    int nnode = min(NR, N - nb0);
    int lo = bstart[b], hi = bstart[b + 1];
    if (t < NR) cnt[t] = 0;
    __syncthreads();
    for (int bb = lo; bb < hi; bb += 2048) {
        int idx = bb + t;
        unsigned pk[8];
        int c = 0;
#pragma unroll
        for (int u = 0; u < 8; u++) {
            int e = idx + u * 256;
            if (e < hi) pk[c++] = packed[e];
        }
        for (int u = 0; u < c; u++) atomicAdd(&cnt[pk[u] >> 17], 1);
    }
    __syncthreads();
    if (t < NR) sc[t] = cnt[t];
    __syncthreads();
    for (int off = 1; off < NR; off <<= 1) {
        int add = (t >= off && t < NR) ? sc[t - off] : 0;
        __syncthreads();
        if (t < NR) sc[t] += add;
        __syncthreads();
    }
    if (t < nnode) {
        int s = lo + sc[t] - cnt[t];
        row_start[nb0 + t] = s;
        cur[t] = s;
    }
    if (t == 0 && nb0 + nnode == N) row_start[N] = hi;
    __syncthreads();
    for (int bb = lo; bb < hi; bb += 2048) {
        int idx = bb + t;
        unsigned pk[8];
        int c = 0;
#pragma unroll
        for (int u = 0; u < 8; u++) {
            int e = idx + u * 256;
            if (e < hi) pk[c++] = packed[e];
        }
        for (int u = 0; u < c; u++) {
            int pos = atomicAdd(&cur[pk[u] >> 17], 1);
            srcs[pos] = (int)(pk[u] & 0x1FFFFu);
        }
    }
}

// ---------------- fused prep: x -> bf16 + all weight transposes ----------------
// Wt0 layout (KT=64, single stage): Wt0[col*64 + ((k + 8*col) & 63)]
// Wt1/Wt2 layout (KT=256, two 32KB halves of 128 k each):
//   h = k>>7; Wt[h*16384 + col*128 + (((k&127) + 8*col) & 127)]
// Wa2t layout (KT=128): Wa2t[col*128 + ((k + 8*col) & 127)]

__global__ void prep_fused(const float* __restrict__ x, ushortT* __restrict__ xbf, int n4,
                           const float* __restrict__ Wl0, const float* __restrict__ Wr0,
                           const float* __restrict__ Wl1, const float* __restrict__ Wr1,
                           const float* __restrict__ Wl2, const float* __restrict__ Wr2,
                           const float* __restrict__ Wa2,
                           ushortT* __restrict__ Wt0, ushortT* __restrict__ Wt1,
                           ushortT* __restrict__ Wt2, ushortT* __restrict__ Wa2t) {
    int tid0 = blockIdx.x * 256 + threadIdx.x;
    if (tid0 < n4) {
        float4 v = ((const float4*)x)[tid0];
        ushort4 o;
        o.x = f32_to_bf16_rne(v.x);
        o.y = f32_to_bf16_rne(v.y);
        o.z = f32_to_bf16_rne(v.z);
        o.w = f32_to_bf16_rne(v.w);
        ((ushort4*)xbf)[tid0] = o;
        return;
    }
    int tid = tid0 - n4;
    if (tid < 8192) {  // Wt0: KH=32, KT=64
        int col = tid >> 6, k = tid & 63;
        float v = (k < 32) ? Wl0[k * 128 + col] : Wr0[(k - 32) * 128 + col];
        Wt0[col * 64 + ((k + 8 * col) & 63)] = f32_to_bf16_rne(v);
    } else if (tid < 8192 + 32768) {  // Wt1
        int j = tid - 8192;
        int col = j >> 8, k = j & 255;
        float v = (k < 128) ? Wl1[k * 128 + col] : Wr1[(k - 128) * 128 + col];
        Wt1[(k >> 7) * 16384 + col * 128 + (((k & 127) + 8 * col) & 127)] = f32_to_bf16_rne(v);
    } else if (tid < 8192 + 65536) {  // Wt2
        int j = tid - 8192 - 32768;
        int col = j >> 8, k = j & 255;
        float v = (k < 128) ? Wl2[k * 128 + col] : Wr2[(k - 128) * 128 + col];
        Wt2[(k >> 7) * 16384 + col * 128 + (((k & 127) + 8 * col) & 127)] = f32_to_bf16_rne(v);
    } else if (tid < 8192 + 65536 + 16384) {  // Wa2t
        int j = tid - 8192 - 65536;
        int col = j >> 7, k = j & 127;
        Wa2t[col * 128 + ((k + 8 * col) & 127)] = f32_to_bf16_rne(Wa2[k * 128 + col]);
    }
}

// ---------------- gather helpers: ping-pong batch pipeline, spill-free -----------------
// fp8 h layout is PERMUTED: feature f stored at byte ((f>>3)&3)*32 + (f>>5)*8 + (f&7),
// so lane q's A-slice (features ks*32+q*8..+8, ks=0..3) is 32 contiguous bytes at q*32.
// Batch of 4 neighbors (8 uint4 in flight) accumulates while the next batch's loads fly.
// Edge order is strictly increasing -> numerics identical to the unfused path.

__device__ __forceinline__ void gather_fp8(const uint4* __restrict__ hp,
                                           const int* __restrict__ srcs,
                                           int lo, int deg, int q, float* ag) {
    if (deg <= 0) return;
    int last = lo + deg - 1;
    int nb = (deg + 3) >> 2;
    uint4 A[8], B[8];
#pragma unroll
    for (int u = 0; u < 4; u++) {
        size_t bs = (size_t)srcs[min(lo + u, last)] * 8 + q * 2;
        A[2 * u] = hp[bs];
        A[2 * u + 1] = hp[bs + 1];
    }
    int b = 0;
    while (true) {
        if (b + 1 < nb) {
#pragma unroll
            for (int u = 0; u < 4; u++) {
                size_t bs = (size_t)srcs[min(lo + (b + 1) * 4 + u, last)] * 8 + q * 2;
                B[2 * u] = hp[bs];
                B[2 * u + 1] = hp[bs + 1];
            }
        }
        int rem = deg - b * 4;
#pragma unroll
        for (int u = 0; u < 4; u++)
            if (u < rem) accum32_fp8(ag, A[2 * u], A[2 * u + 1]);
        b++;
        if (b >= nb) break;
        if (b + 1 < nb) {
#pragma unroll
            for (int u = 0; u < 4; u++) {
                size_t bs = (size_t)srcs[min(lo + (b + 1) * 4 + u, last)] * 8 + q * 2;
                A[2 * u] = hp[bs];
                A[2 * u + 1] = hp[bs + 1];
            }
        }
        rem = deg - b * 4;
#pragma unroll
        for (int u = 0; u < 4; u++)
            if (u < rem) accum32_fp8(ag, B[2 * u], B[2 * u + 1]);
        b++;
        if (b >= nb) break;
    }
}

__device__ __forceinline__ void gather_bf16(const uint4* __restrict__ xp,
                                            const int* __restrict__ srcs,
                                            int lo, int deg, int q, float* ag) {
    if (deg <= 0) return;
    int last = lo + deg - 1;
    int nb = (deg + 7) >> 3;
    uint4 A[8], B[8];
#pragma unroll
    for (int u = 0; u < 8; u++) A[u] = xp[(size_t)srcs[min(lo + u, last)] * 4 + q];
    int b = 0;
    while (true) {
        if (b + 1 < nb) {
#pragma unroll
            for (int u = 0; u < 8; u++)
                B[u] = xp[(size_t)srcs[min(lo + (b + 1) * 8 + u, last)] * 4 + q];
        }
        int rem = deg - b * 8;
#pragma unroll
        for (int u = 0; u < 8; u++)
            if (u < rem) accum8(ag, A[u]);
        b++;
        if (b >= nb) break;
        if (b + 1 < nb) {
#pragma unroll
            for (int u = 0; u < 8; u++)
                A[u] = xp[(size_t)srcs[min(lo + (b + 1) * 8 + u, last)] * 4 + q];
        }
        rem = deg - b * 8;
#pragma unroll
        for (int u = 0; u < 8; u++)
            if (u < rem) accum8(ag, B[u]);
        b++;
        if (b >= nb) break;
    }
}

// ---------------- fused aggregation + MFMA GEMM (BM=64, split-K staging) ---------------
// Each lane owns ONE row (wv*16+cid) and its full A-fragment set.
// 128-K variants pinned at waves_per_eu(4,4): VGPR budget 128 (no spill), 4 blocks/CU.

template <int KH, bool IN_FP8>
__device__ __forceinline__ void gemm_agg_body(
        const void* __restrict__ gat, const ushortT* __restrict__ Ah,
        const int* __restrict__ srcs, const int* __restrict__ rs,
        const ushortT* __restrict__ Wt, const float* __restrict__ bias,
        ushortT* __restrict__ outbf, unsigned char* __restrict__ outf8, int n) {
    constexpr int NKS = KH / 32;
    constexpr int KTH = (KH == 32) ? 64 : 128;   // staged k-extent
    __shared__ __attribute__((aligned(16))) ushortT sW[128 * KTH];
    int t = threadIdx.x;
    {
        const uint4* Wg = (const uint4*)Wt;
        uint4* Ws = (uint4*)sW;
#pragma unroll
        for (int j = 0; j < (128 * KTH / 8) / 256; j++) Ws[t + j * 256] = Wg[t + j * 256];
    }
    int wv = t >> 6, lane = t & 63;
    int q = lane >> 4, cid = lane & 15;
    int row = blockIdx.x * 64 + wv * 16 + cid;
    int rc = min(row, n - 1);

    // ---- register aggregation (mean of neighbor rows, this lane's feature slice)
    float ag[NKS * 8];
#pragma unroll
    for (int j = 0; j < NKS * 8; j++) ag[j] = 0.f;
    int lo = rs[rc], deg = rs[rc + 1] - lo;
    if constexpr (IN_FP8) gather_fp8((const uint4*)gat, srcs, lo, deg, q, ag);
    else                  gather_bf16((const uint4*)gat, srcs, lo, deg, q, ag);
    float inv = 1.0f / (float)max(deg, 1);
    short8 am[NKS];
#pragma unroll
    for (int ks = 0; ks < NKS; ks++)
#pragma unroll
        for (int j = 0; j < 8; j++) am[ks][j] = (short)f32_to_bf16_rne(ag[ks * 8 + j] * inv);
    __syncthreads();   // sW (stage 0) ready

    float4v acc[8];
#pragma unroll
    for (int j = 0; j < 8; j++) acc[j] = (float4v){0.f, 0.f, 0.f, 0.f};
    int pbase = q * 8 + 8 * cid;
    // half 0: A = aggregated mean (registers)
#pragma unroll
    for (int ks = 0; ks < NKS; ks++) {
        int p = (ks * 32 + pbase) & (KTH - 1);
#pragma unroll
        for (int j = 0; j < 8; ++j) {
            short8 b = *(const short8*)(sW + (j * 16 + cid) * KTH + p);
            acc[j] = __builtin_amdgcn_mfma_f32_16x16x32_bf16(am[ks], b, acc[j], 0, 0, 0);
        }
    }
    // half 1: A = Ah (global)
    if constexpr (KH == 32) {
        short8 ah = *(const short8*)(Ah + (size_t)rc * 32 + q * 8);
        int p = (32 + pbase) & 63;
#pragma unroll
        for (int j = 0; j < 8; ++j) {
            short8 b = *(const short8*)(sW + (j * 16 + cid) * 64 + p);
            acc[j] = __builtin_amdgcn_mfma_f32_16x16x32_bf16(ah, b, acc[j], 0, 0, 0);
        }
    } else {
        short8 ah[4];
#pragma unroll
        for (int ks = 0; ks < 4; ks++)
            ah[ks] = *(const short8*)(Ah + (size_t)rc * 128 + ks * 32 + q * 8);
        __syncthreads();   // done reading stage 0
        {
            const uint4* Wg = (const uint4*)(Wt + 128 * 128);
            uint4* Ws = (uint4*)sW;
#pragma unroll
            for (int j = 0; j < 8; j++) Ws[t + j * 256] = Wg[t + j * 256];
        }
        __syncthreads();   // stage 1 ready
#pragma unroll
        for (int ks = 0; ks < 4; ks++) {
            int p = (ks * 32 + pbase) & 127;
#pragma unroll
            for (int j = 0; j < 8; ++j) {
                short8 b = *(const short8*)(sW + (j * 16 + cid) * 128 + p);
                acc[j] = __builtin_amdgcn_mfma_f32_16x16x32_bf16(ah[ks], b, acc[j], 0, 0, 0);
            }
        }
    }
    // epilogue: relu + bias; dual-write bf16 (linear) + fp8 (permuted)
    float bo[8];
#pragma unroll
    for (int j = 0; j < 8; ++j) bo[j] = bias[j * 16 + cid];
    int orow = blockIdx.x * 64 + wv * 16 + q * 4;
#pragma unroll
    for (int rr = 0; rr < 4; ++rr) {
        int r = orow + rr;
        if (r < n) {
#pragma unroll
            for (int j = 0; j < 8; ++j) {
                int col = j * 16 + cid;
                float v = fmaxf(acc[j][rr] + bo[j], 0.f);
                outbf[(size_t)r * 128 + col] = f32_to_bf16_rne(v);
                int pc = ((col >> 3) & 3) * 32 + ((col >> 5) << 3) + (col & 7);
                outf8[(size_t)r * 128 + pc] = f32_to_fp8(v);
            }
        }
    }
}

__launch_bounds__(256)
__global__ void gemm_agg32(const void* __restrict__ gat, const ushortT* __restrict__ Ah,
                           const int* __restrict__ srcs, const int* __restrict__ rs,
                           const ushortT* __restrict__ Wt, const float* __restrict__ bias,
                           ushortT* __restrict__ outbf, unsigned char* __restrict__ outf8, int n) {
    gemm_agg_body<32, false>(gat, Ah, srcs, rs, Wt, bias, outbf, outf8, n);
}

__launch_bounds__(256) __attribute__((amdgpu_waves_per_eu(4, 4)))
__global__ void gemm_agg128(const void* __restrict__ gat, const ushortT* __restrict__ Ah,
                            const int* __restrict__ srcs, const int* __restrict__ rs,
                            const ushortT* __restrict__ Wt, const float* __restrict__ bias,
                            ushortT* __restrict__ outbf, unsigned char* __restrict__ outf8, int n) {
    gemm_agg_body<128, true>(gat, Ah, srcs, rs, Wt, bias, outbf, outf8, n);
}

// ---- layer-2 variant: fused aggregation + GEMM + d1/d3 epilogue + aux-head MLP --------

__launch_bounds__(256) __attribute__((amdgpu_waves_per_eu(4, 4)))
__global__ void gemm_agg_fin(const void* __restrict__ gat, const ushortT* __restrict__ Ah,
                             const int* __restrict__ srcs, const int* __restrict__ rs,
                             const ushortT* __restrict__ Wt, const float* __restrict__ bias,
                             const float* __restrict__ Wfc, const float* __restrict__ bfc,
                             const ushortT* __restrict__ Wa2t, const float* __restrict__ Wa1,
                             const float* __restrict__ ba1, const float* __restrict__ ba2,
                             const float* __restrict__ Wao, const float* __restrict__ bao,
                             float* __restrict__ fin, int n) {
    __shared__ __attribute__((aligned(16))) ushortT sW[128 * 128];   // 32 KB
    __shared__ float sD1[64], sD3[64];
    __shared__ float sWa1a[128], sWa1b[128], sBa1[128];
    int t = threadIdx.x;
    {
        const uint4* Wg = (const uint4*)Wt;
        uint4* Ws = (uint4*)sW;
#pragma unroll
        for (int j = 0; j < 8; j++) Ws[t + j * 256] = Wg[t + j * 256];
    }
    if (t < 128) { sWa1a[t] = Wa1[t]; sWa1b[t] = Wa1[128 + t]; sBa1[t] = ba1[t]; }
    int wv = t >> 6, lane = t & 63;
    int q = lane >> 4, cid = lane & 15;
    int row = blockIdx.x * 64 + wv * 16 + cid;
    int rc = min(row, n - 1);

    float ag[32];
#pragma unroll
    for (int j = 0; j < 32; j++) ag[j] = 0.f;
    int lo = rs[rc], deg = rs[rc + 1] - lo;
    gather_fp8((const uint4*)gat, srcs, lo, deg, q, ag);
    float inv = 1.0f / (float)max(deg, 1);
    short8 am[4];
#pragma unroll
    for (int ks = 0; ks < 4; ks++)
#pragma unroll
        for (int j = 0; j < 8; j++) am[ks][j] = (short)f32_to_bf16_rne(ag[ks * 8 + j] * inv);
    __syncthreads();   // sW stage 0 ready

    float4v acc[8];
#pragma unroll
    for (int j = 0; j < 8; j++) acc[j] = (float4v){0.f, 0.f, 0.f, 0.f};
    int pbase = q * 8 + 8 * cid;
#pragma unroll
    for (int ks = 0; ks < 4; ks++) {
        int p = (ks * 32 + pbase) & 127;
#pragma unroll
        for (int j = 0; j < 8; ++j) {
            short8 b = *(const short8*)(sW + (j * 16 + cid) * 128 + p);
            acc[j] = __builtin_amdgcn_mfma_f32_16x16x32_bf16(am[ks], b, acc[j], 0, 0, 0);
        }
    }
    short8 ah[4];
#pragma unroll
    for (int ks = 0; ks < 4; ks++)
        ah[ks] = *(const short8*)(Ah + (size_t)rc * 128 + ks * 32 + q * 8);
    __syncthreads();
    {
        const uint4* Wg = (const uint4*)(Wt + 128 * 128);
        uint4* Ws = (uint4*)sW;
#pragma unroll
        for (int j = 0; j < 8; j++) Ws[t + j * 256] = Wg[t + j * 256];
    }
    __syncthreads();
#pragma unroll
    for (int ks = 0; ks < 4; ks++) {
        int p = (ks * 32 + pbase) & 127;
#pragma unroll
        for (int j = 0; j < 8; ++j) {
            short8 b = *(const short8*)(sW + (j * 16 + cid) * 128 + p);
            acc[j] = __builtin_amdgcn_mfma_f32_16x16x32_bf16(ah[ks], b, acc[j], 0, 0, 0);
        }
    }

    // ---- epilogue: d1/d3 -> fin[:,0], fin[:,2] + block-local LDS
    float bo[8], w1[8], w3[8];
#pragma unroll
    for (int j = 0; j < 8; ++j) {
        int col = j * 16 + cid;
        bo[j] = bias[col];
        w1[j] = Wfc[col * 3 + 0];
        w3[j] = Wfc[col * 3 + 2];
    }
    float bfc0 = bfc[0], bfc2 = bfc[2];
#pragma unroll
    for (int rr = 0; rr < 4; ++rr) {
        float p1 = 0.f, p3 = 0.f;
#pragma unroll
        for (int j = 0; j < 8; ++j) {
            float v = fmaxf(acc[j][rr] + bo[j], 0.f);
            p1 += v * w1[j];
            p3 += v * w3[j];
        }
        p1 += __shfl_xor(p1, 1, 64); p3 += __shfl_xor(p3, 1, 64);
        p1 += __shfl_xor(p1, 2, 64); p3 += __shfl_xor(p3, 2, 64);
        p1 += __shfl_xor(p1, 4, 64); p3 += __shfl_xor(p3, 4, 64);
        p1 += __shfl_xor(p1, 8, 64); p3 += __shfl_xor(p3, 8, 64);
        if (cid == 0) {
            int rowl = wv * 16 + q * 4 + rr;
            float d1 = p1 + bfc0, d3 = p3 + bfc2;
            sD1[rowl] = d1;
            sD3[rowl] = d3;
            int r = blockIdx.x * 64 + rowl;
            if (r < n) {
                fin[(size_t)r * 3 + 0] = d1;
                fin[(size_t)r * 3 + 2] = d3;
            }
        }
    }
    __syncthreads();   // sD ready; everyone done reading sW
    {
        const uint4* Wg = (const uint4*)Wa2t;
        uint4* Ws = (uint4*)sW;
#pragma unroll
        for (int j = 0; j < 8; j++) Ws[t + j * 256] = Wg[t + j * 256];
    }
    __syncthreads();

    // ---- aux head: a1 built in registers + a2 MFMA + Wao reduce -> fin[:,1]
    int rl = wv * 16 + cid;
    float d1a = sD1[rl], d3a = sD3[rl];
    float4v hacc[8];
#pragma unroll
    for (int j = 0; j < 8; j++) hacc[j] = (float4v){0.f, 0.f, 0.f, 0.f};
#pragma unroll
    for (int ks = 0; ks < 4; ++ks) {
        int k0 = ks * 32 + q * 8;
        short8 a0;
#pragma unroll
        for (int j = 0; j < 8; ++j) {
            int k = k0 + j;
            float v0 = fmaxf(fmaf(d1a, sWa1a[k], fmaf(d3a, sWa1b[k], sBa1[k])), 0.f);
            a0[j] = (short)f32_to_bf16_rne(v0);
        }
        int p = (ks * 32 + pbase) & 127;
#pragma unroll
        for (int j = 0; j < 8; ++j) {
            short8 b = *(const short8*)(sW + (j * 16 + cid) * 128 + p);
            hacc[j] = __builtin_amdgcn_mfma_f32_16x16x32_bf16(a0, b, hacc[j], 0, 0, 0);
        }
    }
    float b2[8], wo[8];
#pragma unroll
    for (int j = 0; j < 8; ++j) {
        int col = j * 16 + cid;
        b2[j] = ba2[col];
        wo[j] = Wao[col];
    }
    float bao0 = bao[0];
#pragma unroll
    for (int rr = 0; rr < 4; ++rr) {
        float s = 0.f;
#pragma unroll
        for (int j = 0; j < 8; ++j) s += fmaxf(hacc[j][rr] + b2[j], 0.f) * wo[j];
        s += __shfl_xor(s, 1, 64);
        s += __shfl_xor(s, 2, 64);
        s += __shfl_xor(s, 4, 64);
        s += __shfl_xor(s, 8, 64);
        int r = blockIdx.x * 64 + wv * 16 + q * 4 + rr;
        if (cid == 0 && r < n) fin[(size_t)r * 3 + 1] = s + bao0;
    }
}

// ---------------- per-graph mean pool ----------------

__global__ void pool_kernel(const float* __restrict__ fin, const int* __restrict__ batch,
                            float* __restrict__ out, int n) {
    int g = blockIdx.x, t = threadIdx.x;
    int lo = 0, hi = n;
    while (lo < hi) { int mid = (lo + hi) >> 1; if (batch[mid] < g) lo = mid + 1; else hi = mid; }
    int start = lo;
    lo = 0; hi = n;
    while (lo < hi) { int mid = (lo + hi) >> 1; if (batch[mid] < g + 1) lo = mid + 1; else hi = mid; }
    int end = lo;
    float s0 = 0.f, s1 = 0.f, s2 = 0.f;
    for (int i = start + t; i < end; i += 256) {
        s0 += fin[(size_t)i * 3 + 0];
        s1 += fin[(size_t)i * 3 + 1];
        s2 += fin[(size_t)i * 3 + 2];
    }
    __shared__ float r0[256], r1[256], r2[256];
    r0[t] = s0; r1[t] = s1; r2[t] = s2;
    __syncthreads();
    for (int off = 128; off > 0; off >>= 1) {
        if (t < off) { r0[t] += r0[t + off]; r1[t] += r1[t + off]; r2[t] += r2[t + off]; }
        __syncthreads();
    }
    if (t == 0) {
        float c = (float)max(end - start, 1);
        out[g * 3 + 0] = r0[0] / c;
        out[g * 3 + 1] = r1[0] / c;
        out[g * 3 + 2] = r2[0] / c;
    }
}

// ---------------- launch ----------------

extern "C" void kernel_launch(void* const* d_in, const int* in_sizes, int n_in,
                              void* d_out, int out_size, void* d_ws, size_t ws_size,
                              hipStream_t stream) {
    const float* x    = (const float*)d_in[0];
    const int*   ei   = (const int*)d_in[1];
    const int*   batch= (const int*)d_in[2];
    const float* Wl0  = (const float*)d_in[3];
    const float* bl0  = (const float*)d_in[4];
    const float* Wr0  = (const float*)d_in[5];
    const float* Wl1  = (const float*)d_in[6];
    const float* bl1  = (const float*)d_in[7];
    const float* Wr1  = (const float*)d_in[8];
    const float* Wl2  = (const float*)d_in[9];
    const float* bl2  = (const float*)d_in[10];
    const float* Wr2  = (const float*)d_in[11];
    const float* Wfc  = (const float*)d_in[12];
    const float* bfc  = (const float*)d_in[13];
    const float* Wa1  = (const float*)d_in[14];
    const float* ba1  = (const float*)d_in[15];
    const float* Wa2  = (const float*)d_in[16];
    const float* ba2  = (const float*)d_in[17];
    const float* Wao  = (const float*)d_in[18];
    const float* bao  = (const float*)d_in[19];

    const int N = in_sizes[0] / 32;
    const int E = in_sizes[1] / 2;
    const int G = out_size / 3;
    const int* src = ei;
    const int* dst = ei + E;
    float* out = (float*)d_out;
    const int NB = (N + NR - 1) / NR;

    char* p = (char*)d_ws;
    auto carve = [&](size_t bytes) {
        void* r = (void*)p;
        p += (bytes + 255) & ~(size_t)255;
        return r;
    };
    int*           bcnt     = (int*)carve((size_t)NB * 4);
    int*           bstart   = (int*)carve((size_t)(NB + 1) * 4);
    int*           gcur     = (int*)carve((size_t)NB * 4);
    int*           row_start= (int*)carve((size_t)(N + 1) * 4);
    unsigned*      packed   = (unsigned*)carve((size_t)E * 4);
    int*           srcs     = (int*)carve((size_t)E * 4);
    ushortT*       xbf      = (ushortT*)carve((size_t)N * 32 * 2);
    ushortT*       hbf0     = (ushortT*)carve((size_t)N * 128 * 2);
    ushortT*       hbf1     = (ushortT*)carve((size_t)N * 128 * 2);
    unsigned char* hf8_0    = (unsigned char*)carve((size_t)N * 128);
    unsigned char* hf8_1    = (unsigned char*)carve((size_t)N * 128);
    float*         fin      = (float*)carve((size_t)N * 3 * 4);
    ushortT*       Wt0      = (ushortT*)carve((size_t)128 * 64 * 2);
    ushortT*       Wt1      = (ushortT*)carve((size_t)128 * 256 * 2);
    ushortT*       Wt2      = (ushortT*)carve((size_t)128 * 256 * 2);
    ushortT*       Wa2t     = (ushortT*)carve((size_t)128 * 128 * 2);

    const int gemm_grid = (N + 63) / 64;
    const int part_grid = (E + PART_CH - 1) / PART_CH;
    const int n4 = N * 32 / 4;

    // fused input/weight prep
    prep_fused<<<(n4 + 90112 + 255) / 256, 256, 0, stream>>>(
        x, xbf, n4, Wl0, Wr0, Wl1, Wr1, Wl2, Wr2, Wa2, Wt0, Wt1, Wt2, Wa2t);

    // CSR build
    hipMemsetAsync(bcnt, 0, (size_t)NB * 4, stream);
    bucket_count<<<part_grid, 256, 0, stream>>>(dst, bcnt, E, NB);
    bucket_scan<<<1, 256, 0, stream>>>(bcnt, bstart, gcur, NB, E);
    partition_edges<<<part_grid, 256, 0, stream>>>(src, dst, gcur, packed, E, NB);
    bucket_sort<<<NB, 256, 0, stream>>>(packed, bstart, row_start, srcs, N);

    // layer 0 (KH=32): fused bf16 gather + GEMM; dual-write h0 (bf16 + permuted fp8)
    gemm_agg32<<<gemm_grid, 256, 0, stream>>>(
        (const void*)xbf, xbf, srcs, row_start, Wt0, bl0, hbf0, hf8_0, N);
    // layer 1 (KH=128): fused fp8 gather + GEMM; dual-write h1
    gemm_agg128<<<gemm_grid, 256, 0, stream>>>(
        (const void*)hf8_0, hbf0, srcs, row_start, Wt1, bl1, hbf1, hf8_1, N);
    // layer 2 (KH=128): fused fp8 gather + GEMM + d1/d3 epilogue + aux head -> fin
    gemm_agg_fin<<<gemm_grid, 256, 0, stream>>>(
        (const void*)hf8_1, hbf1, srcs, row_start, Wt2, bl2, Wfc, bfc,
        Wa2t, Wa1, ba1, ba2, Wao, bao, fin, N);

    // per-graph mean pool
    pool_kernel<<<G, 256, 0, stream>>>(fin, batch, out, N);
}

// Round 4
// 331.315 us; speedup vs baseline: 1.2343x; 1.0809x over previous
//
#include <hip/hip_runtime.h>

#define NR 128        // dst nodes per bucket
#define PART_CH 4096  // edges per partition/count block
typedef unsigned short ushortT;
typedef __attribute__((ext_vector_type(8))) short short8;
typedef __attribute__((ext_vector_type(4))) float float4v;
typedef __attribute__((ext_vector_type(2))) float float2v;

__device__ __forceinline__ unsigned short f32_to_bf16_rne(float f) {
    unsigned u = __float_as_uint(f);
    unsigned r = (u + 0x7fffu + ((u >> 16) & 1u)) >> 16;
    return (unsigned short)r;
}

__device__ __forceinline__ unsigned char f32_to_fp8(float f) {
    return (unsigned char)(__builtin_amdgcn_cvt_pk_fp8_f32(f, f, 0, false) & 0xff);
}

__device__ __forceinline__ void accum8(float* acc, uint4 v) {
    unsigned u[4] = {v.x, v.y, v.z, v.w};
#pragma unroll
    for (int q = 0; q < 4; q++) {
        acc[2 * q]     += __uint_as_float(u[q] << 16);
        acc[2 * q + 1] += __uint_as_float(u[q] & 0xffff0000u);
    }
}

// 32 fp8 bytes (two uint4, lane's contiguous permuted slice) -> ag[32]
__device__ __forceinline__ void accum32_fp8(float* ag, uint4 A, uint4 B) {
    unsigned w[8] = {A.x, A.y, A.z, A.w, B.x, B.y, B.z, B.w};
#pragma unroll
    for (int m = 0; m < 8; m++) {
        float2v lo = __builtin_amdgcn_cvt_pk_f32_fp8(w[m], false);
        float2v hi = __builtin_amdgcn_cvt_pk_f32_fp8(w[m], true);
        ag[4 * m + 0] += lo.x;
        ag[4 * m + 1] += lo.y;
        ag[4 * m + 2] += hi.x;
        ag[4 * m + 3] += hi.y;
    }
}

// ---------------- CSR build: bucketed counting sort ----------------

__launch_bounds__(256)
__global__ void bucket_count(const int* __restrict__ dst, int* __restrict__ bcnt, int E, int NB) {
    __shared__ int h[1024];
    int t = threadIdx.x;
    for (int j = t; j < NB; j += 256) h[j] = 0;
    __syncthreads();
    int e0 = blockIdx.x * PART_CH;
    int e1 = min(e0 + PART_CH, E);
    for (int base = e0; base < e1; base += 2048) {
        int idx = base + t;
        int d[8];
        int cnt = 0;
#pragma unroll
        for (int u = 0; u < 8; u++) {
            int e = idx + u * 256;
            if (e < e1) d[cnt++] = dst[e];
        }
        for (int u = 0; u < cnt; u++) atomicAdd(&h[d[u] >> 7], 1);
    }
    __syncthreads();
    for (int j = t; j < NB; j += 256) {
        int v = h[j];
        if (v) atomicAdd(&bcnt[j], v);
    }
}

__launch_bounds__(256)
__global__ void bucket_scan(const int* __restrict__ bcnt, int* __restrict__ bstart,
                            int* __restrict__ gcur, int NB, int E) {
    __shared__ int sh[256];
    int t = threadIdx.x;
    int v[4];
    int tot = 0;
#pragma unroll
    for (int j = 0; j < 4; j++) {
        int idx = t * 4 + j;
        v[j] = (idx < NB) ? bcnt[idx] : 0;
        tot += v[j];
    }
    sh[t] = tot;
    __syncthreads();
    for (int off = 1; off < 256; off <<= 1) {
        int add = (t >= off) ? sh[t - off] : 0;
        __syncthreads();
        sh[t] += add;
        __syncthreads();
    }
    int run = sh[t] - tot;
#pragma unroll
    for (int j = 0; j < 4; j++) {
        int idx = t * 4 + j;
        if (idx < NB) { bstart[idx] = run; gcur[idx] = run; }
        run += v[j];
    }
    if (t == 0) bstart[NB] = E;
}

__launch_bounds__(256)
__global__ void partition_edges(const int* __restrict__ src, const int* __restrict__ dst,
                                int* __restrict__ gcur, unsigned* __restrict__ packed,
                                int E, int NB) {
    __shared__ int hist[1024];
    __shared__ int base[1024];
    int t = threadIdx.x;
    int e0 = blockIdx.x * PART_CH;
    int e1 = min(e0 + PART_CH, E);
    for (int j = t; j < NB; j += 256) hist[j] = 0;
    __syncthreads();
    for (int bb = e0; bb < e1; bb += 2048) {
        int idx = bb + t;
        int d[8];
        int cnt = 0;
#pragma unroll
        for (int u = 0; u < 8; u++) {
            int e = idx + u * 256;
            if (e < e1) d[cnt++] = dst[e];
        }
        for (int u = 0; u < cnt; u++) atomicAdd(&hist[d[u] >> 7], 1);
    }
    __syncthreads();
    for (int j = t; j < NB; j += 256) {
        int h = hist[j];
        base[j] = h ? atomicAdd(&gcur[j], h) : 0;
    }
    __syncthreads();
    for (int j = t; j < NB; j += 256) hist[j] = base[j];
    __syncthreads();
    for (int bb = e0; bb < e1; bb += 2048) {
        int idx = bb + t;
        int d[8], s[8];
        int cnt = 0;
#pragma unroll
        for (int u = 0; u < 8; u++) {
            int e = idx + u * 256;
            if (e < e1) { d[cnt] = dst[e]; s[cnt] = src[e]; cnt++; }
        }
        for (int u = 0; u < cnt; u++) {
            int dd = d[u];
            int pos = atomicAdd(&hist[dd >> 7], 1);
            packed[pos] = (unsigned)s[u] | ((unsigned)(dd & (NR - 1)) << 17);
        }
    }
}

__launch_bounds__(256)
__global__ void bucket_sort(const unsigned* __restrict__ packed, const int* __restrict__ bstart,
                            int* __restrict__ row_start, int* __restrict__ srcs, int N) {
    __shared__ int cnt[NR];
    __shared__ int sc[NR];
    __shared__ int cur[NR];
    int b = blockIdx.x, t = threadIdx.x;
    int nb0 = b * NR;
    int nnode = min(NR, N - nb0);
    int lo = bstart[b], hi = bstart[b + 1];
    if (t < NR) cnt[t] = 0;
    __syncthreads();
    for (int bb = lo; bb < hi; bb += 2048) {
        int idx = bb + t;
        unsigned pk[8];
        int c = 0;
#pragma unroll
        for (int u = 0; u < 8; u++) {
            int e = idx + u * 256;
            if (e < hi) pk[c++] = packed[e];
        }
        for (int u = 0; u < c; u++) atomicAdd(&cnt[pk[u] >> 17], 1);
    }
    __syncthreads();
    if (t < NR) sc[t] = cnt[t];
    __syncthreads();
    for (int off = 1; off < NR; off <<= 1) {
        int add = (t >= off && t < NR) ? sc[t - off] : 0;
        __syncthreads();
        if (t < NR) sc[t] += add;
        __syncthreads();
    }
    if (t < nnode) {
        int s = lo + sc[t] - cnt[t];
        row_start[nb0 + t] = s;
        cur[t] = s;
    }
    if (t == 0 && nb0 + nnode == N) row_start[N] = hi;
    __syncthreads();
    for (int bb = lo; bb < hi; bb += 2048) {
        int idx = bb + t;
        unsigned pk[8];
        int c = 0;
#pragma unroll
        for (int u = 0; u < 8; u++) {
            int e = idx + u * 256;
            if (e < hi) pk[c++] = packed[e];
        }
        for (int u = 0; u < c; u++) {
            int pos = atomicAdd(&cur[pk[u] >> 17], 1);
            srcs[pos] = (int)(pk[u] & 0x1FFFFu);
        }
    }
}

// ---------------- fused prep: x -> bf16 + all weight transposes ----------------
// Wt0 layout (KT=64, single stage): Wt0[col*64 + ((k + 8*col) & 63)]
// Wt1/Wt2 layout (KT=256, two 32KB halves of 128 k each):
//   h = k>>7; Wt[h*16384 + col*128 + (((k&127) + 8*col) & 127)]
// Wa2t layout (KT=128): Wa2t[col*128 + ((k + 8*col) & 127)]

__global__ void prep_fused(const float* __restrict__ x, ushortT* __restrict__ xbf, int n4,
                           const float* __restrict__ Wl0, const float* __restrict__ Wr0,
                           const float* __restrict__ Wl1, const float* __restrict__ Wr1,
                           const float* __restrict__ Wl2, const float* __restrict__ Wr2,
                           const float* __restrict__ Wa2,
                           ushortT* __restrict__ Wt0, ushortT* __restrict__ Wt1,
                           ushortT* __restrict__ Wt2, ushortT* __restrict__ Wa2t) {
    int tid0 = blockIdx.x * 256 + threadIdx.x;
    if (tid0 < n4) {
        float4 v = ((const float4*)x)[tid0];
        ushort4 o;
        o.x = f32_to_bf16_rne(v.x);
        o.y = f32_to_bf16_rne(v.y);
        o.z = f32_to_bf16_rne(v.z);
        o.w = f32_to_bf16_rne(v.w);
        ((ushort4*)xbf)[tid0] = o;
        return;
    }
    int tid = tid0 - n4;
    if (tid < 8192) {  // Wt0: KH=32, KT=64
        int col = tid >> 6, k = tid & 63;
        float v = (k < 32) ? Wl0[k * 128 + col] : Wr0[(k - 32) * 128 + col];
        Wt0[col * 64 + ((k + 8 * col) & 63)] = f32_to_bf16_rne(v);
    } else if (tid < 8192 + 32768) {  // Wt1
        int j = tid - 8192;
        int col = j >> 8, k = j & 255;
        float v = (k < 128) ? Wl1[k * 128 + col] : Wr1[(k - 128) * 128 + col];
        Wt1[(k >> 7) * 16384 + col * 128 + (((k & 127) + 8 * col) & 127)] = f32_to_bf16_rne(v);
    } else if (tid < 8192 + 65536) {  // Wt2
        int j = tid - 8192 - 32768;
        int col = j >> 8, k = j & 255;
        float v = (k < 128) ? Wl2[k * 128 + col] : Wr2[(k - 128) * 128 + col];
        Wt2[(k >> 7) * 16384 + col * 128 + (((k & 127) + 8 * col) & 127)] = f32_to_bf16_rne(v);
    } else if (tid < 8192 + 65536 + 16384) {  // Wa2t
        int j = tid - 8192 - 65536;
        int col = j >> 7, k = j & 127;
        Wa2t[col * 128 + ((k + 8 * col) & 127)] = f32_to_bf16_rne(Wa2[k * 128 + col]);
    }
}

// ---------------- gather helpers: ping-pong batch pipeline, spill-free -----------------
// fp8 h layout is PERMUTED: feature f stored at byte ((f>>3)&3)*32 + (f>>5)*8 + (f&7),
// so lane q's A-slice (features ks*32+q*8..+8, ks=0..3) is 32 contiguous bytes at q*32.
// Batch of 4 neighbors (8 uint4 in flight) accumulates while the next batch's loads fly.
// Edge order is strictly increasing -> numerics identical to the unfused path.

__device__ __forceinline__ void gather_fp8(const uint4* __restrict__ hp,
                                           const int* __restrict__ srcs,
                                           int lo, int deg, int q, float* ag) {
    if (deg <= 0) return;
    int last = lo + deg - 1;
    int nb = (deg + 3) >> 2;
    uint4 A[8], B[8];
#pragma unroll
    for (int u = 0; u < 4; u++) {
        size_t bs = (size_t)srcs[min(lo + u, last)] * 8 + q * 2;
        A[2 * u] = hp[bs];
        A[2 * u + 1] = hp[bs + 1];
    }
    int b = 0;
    while (true) {
        if (b + 1 < nb) {
#pragma unroll
            for (int u = 0; u < 4; u++) {
                size_t bs = (size_t)srcs[min(lo + (b + 1) * 4 + u, last)] * 8 + q * 2;
                B[2 * u] = hp[bs];
                B[2 * u + 1] = hp[bs + 1];
            }
        }
        int rem = deg - b * 4;
#pragma unroll
        for (int u = 0; u < 4; u++)
            if (u < rem) accum32_fp8(ag, A[2 * u], A[2 * u + 1]);
        b++;
        if (b >= nb) break;
        if (b + 1 < nb) {
#pragma unroll
            for (int u = 0; u < 4; u++) {
                size_t bs = (size_t)srcs[min(lo + (b + 1) * 4 + u, last)] * 8 + q * 2;
                A[2 * u] = hp[bs];
                A[2 * u + 1] = hp[bs + 1];
            }
        }
        rem = deg - b * 4;
#pragma unroll
        for (int u = 0; u < 4; u++)
            if (u < rem) accum32_fp8(ag, B[2 * u], B[2 * u + 1]);
        b++;
        if (b >= nb) break;
    }
}

__device__ __forceinline__ void gather_bf16(const uint4* __restrict__ xp,
                                            const int* __restrict__ srcs,
                                            int lo, int deg, int q, float* ag) {
    if (deg <= 0) return;
    int last = lo + deg - 1;
    int nb = (deg + 7) >> 3;
    uint4 A[8], B[8];
#pragma unroll
    for (int u = 0; u < 8; u++) A[u] = xp[(size_t)srcs[min(lo + u, last)] * 4 + q];
    int b = 0;
    while (true) {
        if (b + 1 < nb) {
#pragma unroll
            for (int u = 0; u < 8; u++)
                B[u] = xp[(size_t)srcs[min(lo + (b + 1) * 8 + u, last)] * 4 + q];
        }
        int rem = deg - b * 8;
#pragma unroll
        for (int u = 0; u < 8; u++)
            if (u < rem) accum8(ag, A[u]);
        b++;
        if (b >= nb) break;
        if (b + 1 < nb) {
#pragma unroll
            for (int u = 0; u < 8; u++)
                A[u] = xp[(size_t)srcs[min(lo + (b + 1) * 8 + u, last)] * 4 + q];
        }
        rem = deg - b * 8;
#pragma unroll
        for (int u = 0; u < 8; u++)
            if (u < rem) accum8(ag, B[u]);
        b++;
        if (b >= nb) break;
    }
}

// ---------------- fused aggregation + MFMA GEMM (BM=64, split-K staging) ---------------
// Each lane owns ONE row (wv*16+cid) and its full A-fragment set.
// __launch_bounds__(256, 2): min 2 waves/EU -> 256-VGPR budget; allocator lands ~120
// (R1-measured: VGPR=120, WRITE_SIZE=1.2MB, no spill) => 4 blocks/CU with 34KB LDS.

template <int KH, bool IN_FP8>
__device__ __forceinline__ void gemm_agg_body(
        const void* __restrict__ gat, const ushortT* __restrict__ Ah,
        const int* __restrict__ srcs, const int* __restrict__ rs,
        const ushortT* __restrict__ Wt, const float* __restrict__ bias,
        ushortT* __restrict__ outbf, unsigned char* __restrict__ outf8, int n) {
    constexpr int NKS = KH / 32;
    constexpr int KTH = (KH == 32) ? 64 : 128;   // staged k-extent
    __shared__ __attribute__((aligned(16))) ushortT sW[128 * KTH];
    int t = threadIdx.x;
    {
        const uint4* Wg = (const uint4*)Wt;
        uint4* Ws = (uint4*)sW;
#pragma unroll
        for (int j = 0; j < (128 * KTH / 8) / 256; j++) Ws[t + j * 256] = Wg[t + j * 256];
    }
    int wv = t >> 6, lane = t & 63;
    int q = lane >> 4, cid = lane & 15;
    int row = blockIdx.x * 64 + wv * 16 + cid;
    int rc = min(row, n - 1);

    // ---- register aggregation (mean of neighbor rows, this lane's feature slice)
    float ag[NKS * 8];
#pragma unroll
    for (int j = 0; j < NKS * 8; j++) ag[j] = 0.f;
    int lo = rs[rc], deg = rs[rc + 1] - lo;
    if constexpr (IN_FP8) gather_fp8((const uint4*)gat, srcs, lo, deg, q, ag);
    else                  gather_bf16((const uint4*)gat, srcs, lo, deg, q, ag);
    float inv = 1.0f / (float)max(deg, 1);
    short8 am[NKS];
#pragma unroll
    for (int ks = 0; ks < NKS; ks++)
#pragma unroll
        for (int j = 0; j < 8; j++) am[ks][j] = (short)f32_to_bf16_rne(ag[ks * 8 + j] * inv);
    __syncthreads();   // sW (stage 0) ready

    float4v acc[8];
#pragma unroll
    for (int j = 0; j < 8; j++) acc[j] = (float4v){0.f, 0.f, 0.f, 0.f};
    int pbase = q * 8 + 8 * cid;
    // half 0: A = aggregated mean (registers)
#pragma unroll
    for (int ks = 0; ks < NKS; ks++) {
        int p = (ks * 32 + pbase) & (KTH - 1);
#pragma unroll
        for (int j = 0; j < 8; ++j) {
            short8 b = *(const short8*)(sW + (j * 16 + cid) * KTH + p);
            acc[j] = __builtin_amdgcn_mfma_f32_16x16x32_bf16(am[ks], b, acc[j], 0, 0, 0);
        }
    }
    // half 1: A = Ah (global)
    if constexpr (KH == 32) {
        short8 ah = *(const short8*)(Ah + (size_t)rc * 32 + q * 8);
        int p = (32 + pbase) & 63;
#pragma unroll
        for (int j = 0; j < 8; ++j) {
            short8 b = *(const short8*)(sW + (j * 16 + cid) * 64 + p);
            acc[j] = __builtin_amdgcn_mfma_f32_16x16x32_bf16(ah, b, acc[j], 0, 0, 0);
        }
    } else {
        short8 ah[4];
#pragma unroll
        for (int ks = 0; ks < 4; ks++)
            ah[ks] = *(const short8*)(Ah + (size_t)rc * 128 + ks * 32 + q * 8);
        __syncthreads();   // done reading stage 0
        {
            const uint4* Wg = (const uint4*)(Wt + 128 * 128);
            uint4* Ws = (uint4*)sW;
#pragma unroll
            for (int j = 0; j < 8; j++) Ws[t + j * 256] = Wg[t + j * 256];
        }
        __syncthreads();   // stage 1 ready
#pragma unroll
        for (int ks = 0; ks < 4; ks++) {
            int p = (ks * 32 + pbase) & 127;
#pragma unroll
            for (int j = 0; j < 8; ++j) {
                short8 b = *(const short8*)(sW + (j * 16 + cid) * 128 + p);
                acc[j] = __builtin_amdgcn_mfma_f32_16x16x32_bf16(ah[ks], b, acc[j], 0, 0, 0);
            }
        }
    }
    // epilogue: relu + bias; dual-write bf16 (linear) + fp8 (permuted)
    float bo[8];
#pragma unroll
    for (int j = 0; j < 8; ++j) bo[j] = bias[j * 16 + cid];
    int orow = blockIdx.x * 64 + wv * 16 + q * 4;
#pragma unroll
    for (int rr = 0; rr < 4; ++rr) {
        int r = orow + rr;
        if (r < n) {
#pragma unroll
            for (int j = 0; j < 8; ++j) {
                int col = j * 16 + cid;
                float v = fmaxf(acc[j][rr] + bo[j], 0.f);
                outbf[(size_t)r * 128 + col] = f32_to_bf16_rne(v);
                int pc = ((col >> 3) & 3) * 32 + ((col >> 5) << 3) + (col & 7);
                outf8[(size_t)r * 128 + pc] = f32_to_fp8(v);
            }
        }
    }
}

__launch_bounds__(256, 2)
__global__ void gemm_agg32(const void* __restrict__ gat, const ushortT* __restrict__ Ah,
                           const int* __restrict__ srcs, const int* __restrict__ rs,
                           const ushortT* __restrict__ Wt, const float* __restrict__ bias,
                           ushortT* __restrict__ outbf, unsigned char* __restrict__ outf8, int n) {
    gemm_agg_body<32, false>(gat, Ah, srcs, rs, Wt, bias, outbf, outf8, n);
}

__launch_bounds__(256, 2)
__global__ void gemm_agg128(const void* __restrict__ gat, const ushortT* __restrict__ Ah,
                            const int* __restrict__ srcs, const int* __restrict__ rs,
                            const ushortT* __restrict__ Wt, const float* __restrict__ bias,
                            ushortT* __restrict__ outbf, unsigned char* __restrict__ outf8, int n) {
    gemm_agg_body<128, true>(gat, Ah, srcs, rs, Wt, bias, outbf, outf8, n);
}

// ---- layer-2 variant: fused aggregation + GEMM + d1/d3 epilogue + aux-head MLP --------

__launch_bounds__(256, 2)
__global__ void gemm_agg_fin(const void* __restrict__ gat, const ushortT* __restrict__ Ah,
                             const int* __restrict__ srcs, const int* __restrict__ rs,
                             const ushortT* __restrict__ Wt, const float* __restrict__ bias,
                             const float* __restrict__ Wfc, const float* __restrict__ bfc,
                             const ushortT* __restrict__ Wa2t, const float* __restrict__ Wa1,
                             const float* __restrict__ ba1, const float* __restrict__ ba2,
                             const float* __restrict__ Wao, const float* __restrict__ bao,
                             float* __restrict__ fin, int n) {
    __shared__ __attribute__((aligned(16))) ushortT sW[128 * 128];   // 32 KB
    __shared__ float sD1[64], sD3[64];
    __shared__ float sWa1a[128], sWa1b[128], sBa1[128];
    int t = threadIdx.x;
    {
        const uint4* Wg = (const uint4*)Wt;
        uint4* Ws = (uint4*)sW;
#pragma unroll
        for (int j = 0; j < 8; j++) Ws[t + j * 256] = Wg[t + j * 256];
    }
    if (t < 128) { sWa1a[t] = Wa1[t]; sWa1b[t] = Wa1[128 + t]; sBa1[t] = ba1[t]; }
    int wv = t >> 6, lane = t & 63;
    int q = lane >> 4, cid = lane & 15;
    int row = blockIdx.x * 64 + wv * 16 + cid;
    int rc = min(row, n - 1);

    float ag[32];
#pragma unroll
    for (int j = 0; j < 32; j++) ag[j] = 0.f;
    int lo = rs[rc], deg = rs[rc + 1] - lo;
    gather_fp8((const uint4*)gat, srcs, lo, deg, q, ag);
    float inv = 1.0f / (float)max(deg, 1);
    short8 am[4];
#pragma unroll
    for (int ks = 0; ks < 4; ks++)
#pragma unroll
        for (int j = 0; j < 8; j++) am[ks][j] = (short)f32_to_bf16_rne(ag[ks * 8 + j] * inv);
    __syncthreads();   // sW stage 0 ready

    float4v acc[8];
#pragma unroll
    for (int j = 0; j < 8; j++) acc[j] = (float4v){0.f, 0.f, 0.f, 0.f};
    int pbase = q * 8 + 8 * cid;
#pragma unroll
    for (int ks = 0; ks < 4; ks++) {
        int p = (ks * 32 + pbase) & 127;
#pragma unroll
        for (int j = 0; j < 8; ++j) {
            short8 b = *(const short8*)(sW + (j * 16 + cid) * 128 + p);
            acc[j] = __builtin_amdgcn_mfma_f32_16x16x32_bf16(am[ks], b, acc[j], 0, 0, 0);
        }
    }
    short8 ah[4];
#pragma unroll
    for (int ks = 0; ks < 4; ks++)
        ah[ks] = *(const short8*)(Ah + (size_t)rc * 128 + ks * 32 + q * 8);
    __syncthreads();
    {
        const uint4* Wg = (const uint4*)(Wt + 128 * 128);
        uint4* Ws = (uint4*)sW;
#pragma unroll
        for (int j = 0; j < 8; j++) Ws[t + j * 256] = Wg[t + j * 256];
    }
    __syncthreads();
#pragma unroll
    for (int ks = 0; ks < 4; ks++) {
        int p = (ks * 32 + pbase) & 127;
#pragma unroll
        for (int j = 0; j < 8; ++j) {
            short8 b = *(const short8*)(sW + (j * 16 + cid) * 128 + p);
            acc[j] = __builtin_amdgcn_mfma_f32_16x16x32_bf16(ah[ks], b, acc[j], 0, 0, 0);
        }
    }

    // ---- epilogue: d1/d3 -> fin[:,0], fin[:,2] + block-local LDS
    float bo[8], w1[8], w3[8];
#pragma unroll
    for (int j = 0; j < 8; ++j) {
        int col = j * 16 + cid;
        bo[j] = bias[col];
        w1[j] = Wfc[col * 3 + 0];
        w3[j] = Wfc[col * 3 + 2];
    }
    float bfc0 = bfc[0], bfc2 = bfc[2];
#pragma unroll
    for (int rr = 0; rr < 4; ++rr) {
        float p1 = 0.f, p3 = 0.f;
#pragma unroll
        for (int j = 0; j < 8; ++j) {
            float v = fmaxf(acc[j][rr] + bo[j], 0.f);
            p1 += v * w1[j];
            p3 += v * w3[j];
        }
        p1 += __shfl_xor(p1, 1, 64); p3 += __shfl_xor(p3, 1, 64);
        p1 += __shfl_xor(p1, 2, 64); p3 += __shfl_xor(p3, 2, 64);
        p1 += __shfl_xor(p1, 4, 64); p3 += __shfl_xor(p3, 4, 64);
        p1 += __shfl_xor(p1, 8, 64); p3 += __shfl_xor(p3, 8, 64);
        if (cid == 0) {
            int rowl = wv * 16 + q * 4 + rr;
            float d1 = p1 + bfc0, d3 = p3 + bfc2;
            sD1[rowl] = d1;
            sD3[rowl] = d3;
            int r = blockIdx.x * 64 + rowl;
            if (r < n) {
                fin[(size_t)r * 3 + 0] = d1;
                fin[(size_t)r * 3 + 2] = d3;
            }
        }
    }
    __syncthreads();   // sD ready; everyone done reading sW
    {
        const uint4* Wg = (const uint4*)Wa2t;
        uint4* Ws = (uint4*)sW;
#pragma unroll
        for (int j = 0; j < 8; j++) Ws[t + j * 256] = Wg[t + j * 256];
    }
    __syncthreads();

    // ---- aux head: a1 built in registers + a2 MFMA + Wao reduce -> fin[:,1]
    int rl = wv * 16 + cid;
    float d1a = sD1[rl], d3a = sD3[rl];
    float4v hacc[8];
#pragma unroll
    for (int j = 0; j < 8; j++) hacc[j] = (float4v){0.f, 0.f, 0.f, 0.f};
#pragma unroll
    for (int ks = 0; ks < 4; ++ks) {
        int k0 = ks * 32 + q * 8;
        short8 a0;
#pragma unroll
        for (int j = 0; j < 8; ++j) {
            int k = k0 + j;
            float v0 = fmaxf(fmaf(d1a, sWa1a[k], fmaf(d3a, sWa1b[k], sBa1[k])), 0.f);
            a0[j] = (short)f32_to_bf16_rne(v0);
        }
        int p = (ks * 32 + pbase) & 127;
#pragma unroll
        for (int j = 0; j < 8; ++j) {
            short8 b = *(const short8*)(sW + (j * 16 + cid) * 128 + p);
            hacc[j] = __builtin_amdgcn_mfma_f32_16x16x32_bf16(a0, b, hacc[j], 0, 0, 0);
        }
    }
    float b2[8], wo[8];
#pragma unroll
    for (int j = 0; j < 8; ++j) {
        int col = j * 16 + cid;
        b2[j] = ba2[col];
        wo[j] = Wao[col];
    }
    float bao0 = bao[0];
#pragma unroll
    for (int rr = 0; rr < 4; ++rr) {
        float s = 0.f;
#pragma unroll
        for (int j = 0; j < 8; ++j) s += fmaxf(hacc[j][rr] + b2[j], 0.f) * wo[j];
        s += __shfl_xor(s, 1, 64);
        s += __shfl_xor(s, 2, 64);
        s += __shfl_xor(s, 4, 64);
        s += __shfl_xor(s, 8, 64);
        int r = blockIdx.x * 64 + wv * 16 + q * 4 + rr;
        if (cid == 0 && r < n) fin[(size_t)r * 3 + 1] = s + bao0;
    }
}

// ---------------- per-graph mean pool ----------------

__global__ void pool_kernel(const float* __restrict__ fin, const int* __restrict__ batch,
                            float* __restrict__ out, int n) {
    int g = blockIdx.x, t = threadIdx.x;
    int lo = 0, hi = n;
    while (lo < hi) { int mid = (lo + hi) >> 1; if (batch[mid] < g) lo = mid + 1; else hi = mid; }
    int start = lo;
    lo = 0; hi = n;
    while (lo < hi) { int mid = (lo + hi) >> 1; if (batch[mid] < g + 1) lo = mid + 1; else hi = mid; }
    int end = lo;
    float s0 = 0.f, s1 = 0.f, s2 = 0.f;
    for (int i = start + t; i < end; i += 256) {
        s0 += fin[(size_t)i * 3 + 0];
        s1 += fin[(size_t)i * 3 + 1];
        s2 += fin[(size_t)i * 3 + 2];
    }
    __shared__ float r0[256], r1[256], r2[256];
    r0[t] = s0; r1[t] = s1; r2[t] = s2;
    __syncthreads();
    for (int off = 128; off > 0; off >>= 1) {
        if (t < off) { r0[t] += r0[t + off]; r1[t] += r1[t + off]; r2[t] += r2[t + off]; }
        __syncthreads();
    }
    if (t == 0) {
        float c = (float)max(end - start, 1);
        out[g * 3 + 0] = r0[0] / c;
        out[g * 3 + 1] = r1[0] / c;
        out[g * 3 + 2] = r2[0] / c;
    }
}

// ---------------- launch ----------------

extern "C" void kernel_launch(void* const* d_in, const int* in_sizes, int n_in,
                              void* d_out, int out_size, void* d_ws, size_t ws_size,
                              hipStream_t stream) {
    const float* x    = (const float*)d_in[0];
    const int*   ei   = (const int*)d_in[1];
    const int*   batch= (const int*)d_in[2];
    const float* Wl0  = (const float*)d_in[3];
    const float* bl0  = (const float*)d_in[4];
    const float* Wr0  = (const float*)d_in[5];
    const float* Wl1  = (const float*)d_in[6];
    const float* bl1  = (const float*)d_in[7];
    const float* Wr1  = (const float*)d_in[8];
    const float* Wl2  = (const float*)d_in[9];
    const float* bl2  = (const float*)d_in[10];
    const float* Wr2  = (const float*)d_in[11];
    const float* Wfc  = (const float*)d_in[12];
    const float* bfc  = (const float*)d_in[13];
    const float* Wa1  = (const float*)d_in[14];
    const float* ba1  = (const float*)d_in[15];
    const float* Wa2  = (const float*)d_in[16];
    const float* ba2  = (const float*)d_in[17];
    const float* Wao  = (const float*)d_in[18];
    const float* bao  = (const float*)d_in[19];

    const int N = in_sizes[0] / 32;
    const int E = in_sizes[1] / 2;
    const int G = out_size / 3;
    const int* src = ei;
    const int* dst = ei + E;
    float* out = (float*)d_out;
    const int NB = (N + NR - 1) / NR;

    char* p = (char*)d_ws;
    auto carve = [&](size_t bytes) {
        void* r = (void*)p;
        p += (bytes + 255) & ~(size_t)255;
        return r;
    };
    int*           bcnt     = (int*)carve((size_t)NB * 4);
    int*           bstart   = (int*)carve((size_t)(NB + 1) * 4);
    int*           gcur     = (int*)carve((size_t)NB * 4);
    int*           row_start= (int*)carve((size_t)(N + 1) * 4);
    unsigned*      packed   = (unsigned*)carve((size_t)E * 4);
    int*           srcs     = (int*)carve((size_t)E * 4);
    ushortT*       xbf      = (ushortT*)carve((size_t)N * 32 * 2);
    ushortT*       hbf0     = (ushortT*)carve((size_t)N * 128 * 2);
    ushortT*       hbf1     = (ushortT*)carve((size_t)N * 128 * 2);
    unsigned char* hf8_0    = (unsigned char*)carve((size_t)N * 128);
    unsigned char* hf8_1    = (unsigned char*)carve((size_t)N * 128);
    float*         fin      = (float*)carve((size_t)N * 3 * 4);
    ushortT*       Wt0      = (ushortT*)carve((size_t)128 * 64 * 2);
    ushortT*       Wt1      = (ushortT*)carve((size_t)128 * 256 * 2);
    ushortT*       Wt2      = (ushortT*)carve((size_t)128 * 256 * 2);
    ushortT*       Wa2t     = (ushortT*)carve((size_t)128 * 128 * 2);

    const int gemm_grid = (N + 63) / 64;
    const int part_grid = (E + PART_CH - 1) / PART_CH;
    const int n4 = N * 32 / 4;

    // fused input/weight prep
    prep_fused<<<(n4 + 90112 + 255) / 256, 256, 0, stream>>>(
        x, xbf, n4, Wl0, Wr0, Wl1, Wr1, Wl2, Wr2, Wa2, Wt0, Wt1, Wt2, Wa2t);

    // CSR build
    hipMemsetAsync(bcnt, 0, (size_t)NB * 4, stream);
    bucket_count<<<part_grid, 256, 0, stream>>>(dst, bcnt, E, NB);
    bucket_scan<<<1, 256, 0, stream>>>(bcnt, bstart, gcur, NB, E);
    partition_edges<<<part_grid, 256, 0, stream>>>(src, dst, gcur, packed, E, NB);
    bucket_sort<<<NB, 256, 0, stream>>>(packed, bstart, row_start, srcs, N);

    // layer 0 (KH=32): fused bf16 gather + GEMM; dual-write h0 (bf16 + permuted fp8)
    gemm_agg32<<<gemm_grid, 256, 0, stream>>>(
        (const void*)xbf, xbf, srcs, row_start, Wt0, bl0, hbf0, hf8_0, N);
    // layer 1 (KH=128): fused fp8 gather + GEMM; dual-write h1
    gemm_agg128<<<gemm_grid, 256, 0, stream>>>(
        (const void*)hf8_0, hbf0, srcs, row_start, Wt1, bl1, hbf1, hf8_1, N);
    // layer 2 (KH=128): fused fp8 gather + GEMM + d1/d3 epilogue + aux head -> fin
    gemm_agg_fin<<<gemm_grid, 256, 0, stream>>>(
        (const void*)hf8_1, hbf1, srcs, row_start, Wt2, bl2, Wfc, bfc,
        Wa2t, Wa1, ba1, ba2, Wao, bao, fin, N);

    // per-graph mean pool
    pool_kernel<<<G, 256, 0, stream>>>(fin, batch, out, N);
}